// Round 3
// baseline (2454.385 us; speedup 1.0000x reference)
//
#include <hip/hip_runtime.h>

typedef unsigned short u16;
typedef __attribute__((ext_vector_type(4))) float f32x4;
typedef __attribute__((ext_vector_type(8))) short s16x8;

#define T_TOK 8192
#define HD    1024
#define ID    4096
#define NE    8
#define AK    (T_TOK * 2)      // total assignments (top-2)
#define APAD  (AK + 256)       // slack rows: 256-tile A reads may overrun by <=255

#define BAR()   __builtin_amdgcn_s_barrier()
#define SB0()   __builtin_amdgcn_sched_barrier(0)
#define PRIO1() __builtin_amdgcn_s_setprio(1)
#define PRIO0() __builtin_amdgcn_s_setprio(0)
#define WAITV2() asm volatile("s_waitcnt vmcnt(2)" ::: "memory")
#define WAITV0() asm volatile("s_waitcnt vmcnt(0)" ::: "memory")
#define LGKM0()  do { asm volatile("s_waitcnt lgkmcnt(0)" ::: "memory"); SB0(); } while (0)

__device__ __forceinline__ u16 f2bf(float f) {
  unsigned u = __builtin_bit_cast(unsigned, f);
  u += 0x7FFFu + ((u >> 16) & 1u);   // round-to-nearest-even
  return (u16)(u >> 16);
}

__device__ __forceinline__ void gld16(u16* lds, const u16* g) {
  __builtin_amdgcn_global_load_lds(
      (const __attribute__((address_space(1))) unsigned int*)g,
      (__attribute__((address_space(3))) unsigned int*)lds, 16, 0, 0);
}

// ---------------- routing ----------------

__global__ void k_init(int* counts) {
  if (threadIdx.x < NE) counts[threadIdx.x] = 0;
}

__global__ __launch_bounds__(256) void k_router(
    const float* __restrict__ x, const float* __restrict__ wg,
    int* __restrict__ tidx, float* __restrict__ tw, int* __restrict__ counts) {
  __shared__ float wgs[NE * HD];            // transposed [e][h]
  int tid = threadIdx.x;
  for (int i = tid; i < NE * HD; i += 256) {
    int h = i >> 3, e = i & 7;
    wgs[e * HD + h] = wg[i];
  }
  __syncthreads();
  int lane = tid & 63, wid = tid >> 6;
  int t = blockIdx.x * 4 + wid;
  const float* xr = x + (size_t)t * HD;
  double acc[NE];
#pragma unroll
  for (int e = 0; e < NE; ++e) acc[e] = 0.0;
  for (int i = 0; i < HD / 64; ++i) {
    float xv = xr[lane + i * 64];
#pragma unroll
    for (int e = 0; e < NE; ++e)
      acc[e] += (double)xv * (double)wgs[e * HD + lane + i * 64];
  }
#pragma unroll
  for (int e = 0; e < NE; ++e)
    for (int s = 32; s >= 1; s >>= 1) acc[e] += __shfl_xor(acc[e], s, 64);
  int e0 = 0; double m0 = acc[0];
  for (int e = 1; e < NE; ++e) if (acc[e] > m0) { m0 = acc[e]; e0 = e; }
  int e1 = -1; double m1 = -1e300;
  for (int e = 0; e < NE; ++e) if (e != e0 && acc[e] > m1) { m1 = acc[e]; e1 = e; }
  if (lane == 0) {
    double d = exp(m1 - m0);
    tidx[t * 2] = e0; tidx[t * 2 + 1] = e1;
    tw[t * 2] = (float)(1.0 / (1.0 + d));
    tw[t * 2 + 1] = (float)(d / (1.0 + d));
    atomicAdd(&counts[e0], 1);
    atomicAdd(&counts[e1], 1);
  }
}

__global__ void k_offsets(const int* __restrict__ counts, int* offs, int* cursors) {
  if (threadIdx.x == 0) {
    int s = 0;
    for (int e = 0; e < NE; ++e) { offs[e] = s; s += counts[e]; }
    offs[NE] = s;
  }
  if (threadIdx.x < NE) cursors[threadIdx.x] = 0;
}

__global__ __launch_bounds__(256) void k_scatter(
    const int* __restrict__ tidx, const int* __restrict__ offs,
    int* cursors, int* __restrict__ list, int* __restrict__ pos) {
  int idx = blockIdx.x * 256 + threadIdx.x;
  if (idx >= AK) return;
  int e = tidx[idx];
  int p = atomicAdd(&cursors[e], 1);
  int a = offs[e] + p;
  list[a] = idx >> 1;
  pos[idx] = a;
}

// ---------------- fp32 -> bf16 conversion ----------------

__global__ __launch_bounds__(256) void k_cvtx(const float* __restrict__ in,
                                              u16* __restrict__ out) {
  int idx = blockIdx.x * 256 + threadIdx.x;
  const float4* in4 = (const float4*)in;
  float4 v = in4[idx];
  ushort4 o;
  o.x = f2bf(v.x); o.y = f2bf(v.y); o.z = f2bf(v.z); o.w = f2bf(v.w);
  ((ushort4*)out)[idx] = o;
}

// w2 [E][I][H] fp32 -> w2b [E][H][I] bf16 (plain transpose)
__global__ __launch_bounds__(256) void k_tconv(const float* __restrict__ in,
                                               u16* __restrict__ out, int R, int C) {
  __shared__ u16 tile[64][72];
  size_t base = (size_t)blockIdx.z * R * C;
  int r0 = blockIdx.y * 64, c0 = blockIdx.x * 64;
  int t = threadIdx.x;
  int rr = t >> 4;
  int cc = (t & 15) * 4;
#pragma unroll
  for (int i = 0; i < 4; ++i) {
    int r = i * 16 + rr;
    float4 v = *(const float4*)&in[base + (size_t)(r0 + r) * C + c0 + cc];
    tile[cc + 0][r] = f2bf(v.x);
    tile[cc + 1][r] = f2bf(v.y);
    tile[cc + 2][r] = f2bf(v.z);
    tile[cc + 3][r] = f2bf(v.w);
  }
  __syncthreads();
  int c = t >> 3;
  int ch = (t & 7) * 8;
#pragma unroll
  for (int j = 0; j < 2; ++j) {
    int cr = j * 32 + c;
    *(s16x8*)&out[base + (size_t)(c0 + cr) * R + r0 + ch] =
        *(const s16x8*)&tile[cr][ch];
  }
}

// w1/w3 [E][H][I] fp32 -> w13b [E][2I][H] bf16, 16-row interleaved:
// w1 I-row r -> phys (r>>4)*32 + (r&15); w3 I-row r -> +16.
__global__ __launch_bounds__(256) void k_tconv13(const float* __restrict__ w1,
                                                 const float* __restrict__ w3,
                                                 u16* __restrict__ out) {
  __shared__ u16 tile[64][72];
  int which = blockIdx.z >> 3, e = blockIdx.z & 7;
  const float* in = (which ? w3 : w1) + (size_t)e * HD * ID;
  int r0 = blockIdx.y * 64, c0 = blockIdx.x * 64;   // r=H-row, c=I-col
  int t = threadIdx.x;
  int rr = t >> 4;
  int cc = (t & 15) * 4;
#pragma unroll
  for (int i = 0; i < 4; ++i) {
    int r = i * 16 + rr;
    float4 v = *(const float4*)&in[(size_t)(r0 + r) * ID + c0 + cc];
    tile[cc + 0][r] = f2bf(v.x);
    tile[cc + 1][r] = f2bf(v.y);
    tile[cc + 2][r] = f2bf(v.z);
    tile[cc + 3][r] = f2bf(v.w);
  }
  __syncthreads();
  int c = t >> 3;
  int ch = (t & 7) * 8;
#pragma unroll
  for (int j = 0; j < 2; ++j) {
    int crow = c0 + j * 32 + c;                    // I-row
    int pr = ((crow >> 4) << 5) + which * 16 + (crow & 15);
    *(s16x8*)&out[((size_t)e * 2 * ID + pr) * HD + r0 + ch] =
        *(const s16x8*)&tile[j * 32 + c][ch];
  }
}

// ---------------- GEMM1: 8-phase 256x256x64, B = interleaved w13 ----------------
// 8 waves (2M x 4N), wave tile 128x64; fused SwiGLU epilogue (even/odd frag pair).

__global__ __launch_bounds__(512, 2) void k_gemm1(
    const u16* __restrict__ xb, const u16* __restrict__ w13b,
    const int* __restrict__ list, const int* __restrict__ offs,
    u16* __restrict__ hidden) {
  int e = blockIdx.z;
  int aoff = offs[e];
  int cnt = offs[e + 1] - aoff;
  int m0 = blockIdx.x * 256;
  if (m0 >= cnt) return;
  int n0 = blockIdx.y * 256;

  __shared__ u16 As[2][256 * 64];
  __shared__ u16 Bs[2][256 * 64];

  int tid = threadIdx.x, lane = tid & 63, wid = tid >> 6;
  int l8 = lane >> 3, c8 = lane & 7;
  int csrc = (c8 ^ l8) * 8;                 // inverse-swizzled source chunk (T2)

  const u16* gA[4]; const u16* gB[4];
#pragma unroll
  for (int i = 0; i < 4; ++i) {
    int row = i * 64 + wid * 8 + l8;
    int rr = m0 + row; if (rr > cnt - 1) rr = cnt - 1;
    gA[i] = xb + (size_t)list[aoff + rr] * HD + csrc;
    gB[i] = w13b + ((size_t)e * 2 * ID + n0 + row) * HD + csrc;
  }

  f32x4 acc[8][4];
#pragma unroll
  for (int m = 0; m < 8; ++m)
#pragma unroll
    for (int n = 0; n < 4; ++n) acc[m][n] = (f32x4){0.f, 0.f, 0.f, 0.f};

  int wr = wid >> 2, wc = wid & 3;
  int lane15 = lane & 15, lq = lane >> 4, sw8 = lane15 & 7;

#define ST_A(b, kt, h) do { \
    gld16(&As[b][((h)*128 + 0*64 + wid*8) * 64], gA[(h)*2 + 0] + (kt)*64); \
    gld16(&As[b][((h)*128 + 1*64 + wid*8) * 64], gA[(h)*2 + 1] + (kt)*64); } while (0)
#define ST_B(b, kt, h) do { \
    gld16(&Bs[b][((h)*128 + 0*64 + wid*8) * 64], gB[(h)*2 + 0] + (kt)*64); \
    gld16(&Bs[b][((h)*128 + 1*64 + wid*8) * 64], gB[(h)*2 + 1] + (kt)*64); } while (0)
#define RD_A(dst, mm, kk, buf) \
    dst = *(const s16x8*)&As[buf][(wr*128 + (mm)*16 + lane15) * 64 + (((kk)*4 + lq) ^ sw8) * 8]
#define RD_B(dst, nn, kk, buf) \
    dst = *(const s16x8*)&Bs[buf][(wc*64 + (nn)*16 + lane15) * 64 + (((kk)*4 + lq) ^ sw8) * 8]
#define MFMA(m, n, kk, ar, br) \
    acc[m][n] = __builtin_amdgcn_mfma_f32_16x16x32_bf16(ar, br, acc[m][n], 0, 0, 0)

  const int NT = HD / 64;
  ST_A(0, 0, 0); ST_A(0, 0, 1); ST_B(0, 0, 0); ST_B(0, 0, 1);
  s16x8 a[4][2], b[4][2];

  for (int t = 0; t < NT; ++t) {
    int buf = t & 1, nb = buf ^ 1;
    bool pf = (t + 1 < NT);
    // ---- phase 0: A-half0 x B-half0
    if (pf) { ST_A(nb, t + 1, 0); WAITV2(); } else { WAITV0(); }
    BAR(); SB0();
#pragma unroll
    for (int m = 0; m < 4; ++m) { RD_A(a[m][0], m, 0, buf); RD_A(a[m][1], m, 1, buf); }
#pragma unroll
    for (int n = 0; n < 2; ++n) { RD_B(b[n][0], n, 0, buf); RD_B(b[n][1], n, 1, buf); }
    LGKM0(); PRIO1();
#pragma unroll
    for (int m = 0; m < 4; ++m)
#pragma unroll
      for (int n = 0; n < 2; ++n) { MFMA(m, n, 0, a[m][0], b[n][0]); MFMA(m, n, 1, a[m][1], b[n][1]); }
    PRIO0(); BAR();
    // ---- phase 1: A-half0 x B-half1
#pragma unroll
    for (int n = 2; n < 4; ++n) { RD_B(b[n][0], n, 0, buf); RD_B(b[n][1], n, 1, buf); }
    if (pf) ST_A(nb, t + 1, 1);
    BAR(); LGKM0(); PRIO1();
#pragma unroll
    for (int m = 0; m < 4; ++m)
#pragma unroll
      for (int n = 2; n < 4; ++n) { MFMA(m, n, 0, a[m][0], b[n][0]); MFMA(m, n, 1, a[m][1], b[n][1]); }
    PRIO0(); BAR();
    // ---- phase 2: A-half1 x B-half0
#pragma unroll
    for (int m = 0; m < 4; ++m) { RD_A(a[m][0], m + 4, 0, buf); RD_A(a[m][1], m + 4, 1, buf); }
    if (pf) ST_B(nb, t + 1, 0);
    BAR(); LGKM0(); PRIO1();
#pragma unroll
    for (int m = 0; m < 4; ++m)
#pragma unroll
      for (int n = 0; n < 2; ++n) { MFMA(m + 4, n, 0, a[m][0], b[n][0]); MFMA(m + 4, n, 1, a[m][1], b[n][1]); }
    PRIO0(); BAR();
    // ---- phase 3: A-half1 x B-half1
    if (pf) ST_B(nb, t + 1, 1);
    BAR(); PRIO1();
#pragma unroll
    for (int m = 0; m < 4; ++m)
#pragma unroll
      for (int n = 2; n < 4; ++n) { MFMA(m + 4, n, 0, a[m][0], b[n][0]); MFMA(m + 4, n, 1, a[m][1], b[n][1]); }
    PRIO0(); BAR();
  }

  // epilogue: frag pairs (2p, 2p+1) = (w1, w3) for I-block; silu(v1)*v3
#pragma unroll
  for (int m = 0; m < 8; ++m)
#pragma unroll
    for (int j = 0; j < 4; ++j) {
      int grow = m0 + wr * 128 + m * 16 + lq * 4 + j;
      if (grow < cnt) {
        size_t rbase = (size_t)(aoff + grow) * ID;
#pragma unroll
        for (int p = 0; p < 2; ++p) {
          float v1 = acc[m][2 * p][j];
          float v3 = acc[m][2 * p + 1][j];
          float s = v1 / (1.0f + __expf(-v1));
          int icol = (((n0 + wc * 64 + p * 32) >> 5) << 4) + lane15;
          hidden[rbase + icol] = f2bf(s * v3);
        }
      }
    }
#undef ST_A
#undef ST_B
#undef RD_A
#undef RD_B
#undef MFMA
}

// ---------------- GEMM2: 8-phase 256x256x64, y = hidden @ w2 ----------------

__global__ __launch_bounds__(512, 2) void k_gemm2(
    const u16* __restrict__ hidden, const u16* __restrict__ w2b,
    const int* __restrict__ offs, float* __restrict__ y) {
  int e = blockIdx.z;
  int aoff = offs[e];
  int cnt = offs[e + 1] - aoff;
  int m0 = blockIdx.x * 256;
  if (m0 >= cnt) return;
  int n0 = blockIdx.y * 256;

  __shared__ u16 As[2][256 * 64];
  __shared__ u16 Bs[2][256 * 64];

  int tid = threadIdx.x, lane = tid & 63, wid = tid >> 6;
  int l8 = lane >> 3, c8 = lane & 7;
  int csrc = (c8 ^ l8) * 8;

  const u16* gA[4]; const u16* gB[4];
#pragma unroll
  for (int i = 0; i < 4; ++i) {
    int row = i * 64 + wid * 8 + l8;
    gA[i] = hidden + (size_t)(aoff + m0 + row) * ID + csrc;   // APAD slack covers overrun
    gB[i] = w2b + ((size_t)e * HD + n0 + row) * ID + csrc;
  }

  f32x4 acc[8][4];
#pragma unroll
  for (int m = 0; m < 8; ++m)
#pragma unroll
    for (int n = 0; n < 4; ++n) acc[m][n] = (f32x4){0.f, 0.f, 0.f, 0.f};

  int wr = wid >> 2, wc = wid & 3;
  int lane15 = lane & 15, lq = lane >> 4, sw8 = lane15 & 7;

#define ST_A(b, kt, h) do { \
    gld16(&As[b][((h)*128 + 0*64 + wid*8) * 64], gA[(h)*2 + 0] + (kt)*64); \
    gld16(&As[b][((h)*128 + 1*64 + wid*8) * 64], gA[(h)*2 + 1] + (kt)*64); } while (0)
#define ST_B(b, kt, h) do { \
    gld16(&Bs[b][((h)*128 + 0*64 + wid*8) * 64], gB[(h)*2 + 0] + (kt)*64); \
    gld16(&Bs[b][((h)*128 + 1*64 + wid*8) * 64], gB[(h)*2 + 1] + (kt)*64); } while (0)
#define RD_A(dst, mm, kk, buf) \
    dst = *(const s16x8*)&As[buf][(wr*128 + (mm)*16 + lane15) * 64 + (((kk)*4 + lq) ^ sw8) * 8]
#define RD_B(dst, nn, kk, buf) \
    dst = *(const s16x8*)&Bs[buf][(wc*64 + (nn)*16 + lane15) * 64 + (((kk)*4 + lq) ^ sw8) * 8]
#define MFMA(m, n, kk, ar, br) \
    acc[m][n] = __builtin_amdgcn_mfma_f32_16x16x32_bf16(ar, br, acc[m][n], 0, 0, 0)

  const int NT = ID / 64;
  ST_A(0, 0, 0); ST_A(0, 0, 1); ST_B(0, 0, 0); ST_B(0, 0, 1);
  s16x8 a[4][2], b[4][2];

  for (int t = 0; t < NT; ++t) {
    int buf = t & 1, nb = buf ^ 1;
    bool pf = (t + 1 < NT);
    if (pf) { ST_A(nb, t + 1, 0); WAITV2(); } else { WAITV0(); }
    BAR(); SB0();
#pragma unroll
    for (int m = 0; m < 4; ++m) { RD_A(a[m][0], m, 0, buf); RD_A(a[m][1], m, 1, buf); }
#pragma unroll
    for (int n = 0; n < 2; ++n) { RD_B(b[n][0], n, 0, buf); RD_B(b[n][1], n, 1, buf); }
    LGKM0(); PRIO1();
#pragma unroll
    for (int m = 0; m < 4; ++m)
#pragma unroll
      for (int n = 0; n < 2; ++n) { MFMA(m, n, 0, a[m][0], b[n][0]); MFMA(m, n, 1, a[m][1], b[n][1]); }
    PRIO0(); BAR();
#pragma unroll
    for (int n = 2; n < 4; ++n) { RD_B(b[n][0], n, 0, buf); RD_B(b[n][1], n, 1, buf); }
    if (pf) ST_A(nb, t + 1, 1);
    BAR(); LGKM0(); PRIO1();
#pragma unroll
    for (int m = 0; m < 4; ++m)
#pragma unroll
      for (int n = 2; n < 4; ++n) { MFMA(m, n, 0, a[m][0], b[n][0]); MFMA(m, n, 1, a[m][1], b[n][1]); }
    PRIO0(); BAR();
#pragma unroll
    for (int m = 0; m < 4; ++m) { RD_A(a[m][0], m + 4, 0, buf); RD_A(a[m][1], m + 4, 1, buf); }
    if (pf) ST_B(nb, t + 1, 0);
    BAR(); LGKM0(); PRIO1();
#pragma unroll
    for (int m = 0; m < 4; ++m)
#pragma unroll
      for (int n = 0; n < 2; ++n) { MFMA(m + 4, n, 0, a[m][0], b[n][0]); MFMA(m + 4, n, 1, a[m][1], b[n][1]); }
    PRIO0(); BAR();
    if (pf) ST_B(nb, t + 1, 1);
    BAR(); PRIO1();
#pragma unroll
    for (int m = 0; m < 4; ++m)
#pragma unroll
      for (int n = 2; n < 4; ++n) { MFMA(m + 4, n, 0, a[m][0], b[n][0]); MFMA(m + 4, n, 1, a[m][1], b[n][1]); }
    PRIO0(); BAR();
  }

#pragma unroll
  for (int m = 0; m < 8; ++m)
#pragma unroll
    for (int j = 0; j < 4; ++j) {
      int grow = m0 + wr * 128 + m * 16 + lq * 4 + j;
      if (grow < cnt) {
        size_t rbase = (size_t)(aoff + grow) * HD + n0 + wc * 64;
#pragma unroll
        for (int n = 0; n < 4; ++n)
          y[rbase + n * 16 + lane15] = acc[m][n][j];
      }
    }
#undef ST_A
#undef ST_B
#undef RD_A
#undef RD_B
#undef MFMA
}

// ---------------- combine: out[t] = w0*y[pos0] + w1*y[pos1] ----------------

__global__ __launch_bounds__(256) void k_combine(
    const float* __restrict__ y, const int* __restrict__ pos,
    const float* __restrict__ tw, float* __restrict__ out) {
  int t = blockIdx.x;
  int c = threadIdx.x;
  int a0 = pos[t * 2], a1 = pos[t * 2 + 1];
  float w0 = tw[t * 2], w1 = tw[t * 2 + 1];
  float4 v0 = ((const float4*)(y + (size_t)a0 * HD))[c];
  float4 v1 = ((const float4*)(y + (size_t)a1 * HD))[c];
  float4 o;
  o.x = w0 * v0.x + w1 * v1.x;
  o.y = w0 * v0.y + w1 * v1.y;
  o.z = w0 * v0.z + w1 * v1.z;
  o.w = w0 * v0.w + w1 * v1.w;
  ((float4*)(out + (size_t)t * HD))[c] = o;
}

// ---------------- host ----------------

extern "C" void kernel_launch(void* const* d_in, const int* in_sizes, int n_in,
                              void* d_out, int out_size, void* d_ws, size_t ws_size,
                              hipStream_t stream) {
  const float* x  = (const float*)d_in[0];
  const float* wg = (const float*)d_in[1];
  const float* w1 = (const float*)d_in[2];
  const float* w2 = (const float*)d_in[3];
  const float* w3 = (const float*)d_in[4];
  float* out = (float*)d_out;

  char* p = (char*)d_ws;
  auto alloc = [&](size_t bytes) {
    char* r = p;
    p += (bytes + 255) & ~(size_t)255;
    return r;
  };
  u16*   xb      = (u16*)alloc((size_t)T_TOK * HD * 2);           // 16 MiB
  u16*   w13b    = (u16*)alloc((size_t)NE * 2 * ID * HD * 2);     // 128 MiB [E][2I][H] interleaved
  u16*   w2b     = (u16*)alloc((size_t)NE * HD * ID * 2);         // 64 MiB  [E][H][I]
  u16*   hidden  = (u16*)alloc((size_t)APAD * ID * 2);            // 130 MiB
  float* yb      = (float*)alloc((size_t)APAD * HD * 4);          // 65 MiB
  int*   tidx    = (int*)alloc(AK * 4);
  float* tw      = (float*)alloc(AK * 4);
  int*   list    = (int*)alloc(AK * 4);
  int*   pos     = (int*)alloc(AK * 4);
  int*   counts  = (int*)alloc(64);
  int*   offs    = (int*)alloc(64);
  int*   cursors = (int*)alloc(64);
  (void)ws_size; (void)in_sizes; (void)n_in; (void)out_size;

  k_init<<<1, 64, 0, stream>>>(counts);
  k_router<<<T_TOK / 4, 256, 0, stream>>>(x, wg, tidx, tw, counts);
  k_offsets<<<1, 64, 0, stream>>>(counts, offs, cursors);
  k_scatter<<<AK / 256, 256, 0, stream>>>(tidx, offs, cursors, list, pos);

  k_cvtx<<<(T_TOK * HD / 4) / 256, 256, 0, stream>>>(x, xb);
  dim3 g13(ID / 64, HD / 64, 2 * NE);
  k_tconv13<<<g13, 256, 0, stream>>>(w1, w3, w13b);
  dim3 g2(HD / 64, ID / 64, NE);
  k_tconv<<<g2, 256, 0, stream>>>(w2, w2b, ID, HD);    // [I][H] -> [H][I]

  dim3 gg1(T_TOK / 256, 2 * ID / 256, NE);             // x=M (fastest: shares B-panel)
  k_gemm1<<<gg1, 512, 0, stream>>>(xb, w13b, list, offs, hidden);
  dim3 gg2(T_TOK / 256, HD / 256, NE);
  k_gemm2<<<gg2, 512, 0, stream>>>(hidden, w2b, offs, yb);
  k_combine<<<T_TOK, 256, 0, stream>>>(yb, pos, tw, out);
}

// Round 4
// 1190.156 us; speedup vs baseline: 2.0622x; 2.0622x over previous
//
#include <hip/hip_runtime.h>

typedef unsigned short u16;
typedef __attribute__((ext_vector_type(4))) float f32x4;
typedef __attribute__((ext_vector_type(8))) short s16x8;

#define T_TOK 8192
#define HD    1024
#define ID    4096
#define NE    8
#define AK    (T_TOK * 2)      // total assignments (top-2)
#define APAD  (AK + 128)       // slack rows so padded tile reads stay in-buffer

__device__ __forceinline__ u16 f2bf(float f) {
  unsigned u = __builtin_bit_cast(unsigned, f);
  u += 0x7FFFu + ((u >> 16) & 1u);   // round-to-nearest-even
  return (u16)(u >> 16);
}

__device__ __forceinline__ void gld16(u16* lds, const u16* g) {
  __builtin_amdgcn_global_load_lds(
      (const __attribute__((address_space(1))) unsigned int*)g,
      (__attribute__((address_space(3))) unsigned int*)lds, 16, 0, 0);
}

// ---------------- routing ----------------

__global__ void k_init(int* counts) {
  if (threadIdx.x < NE) counts[threadIdx.x] = 0;
}

__global__ __launch_bounds__(256) void k_router(
    const float* __restrict__ x, const float* __restrict__ wg,
    int* __restrict__ tidx, float* __restrict__ tw, int* __restrict__ counts) {
  __shared__ float wgs[NE * HD];            // transposed [e][h]
  int tid = threadIdx.x;
  for (int i = tid; i < NE * HD; i += 256) {
    int h = i >> 3, e = i & 7;
    wgs[e * HD + h] = wg[i];
  }
  __syncthreads();
  int lane = tid & 63, wid = tid >> 6;
  int t = blockIdx.x * 4 + wid;
  const float* xr = x + (size_t)t * HD;
  double acc[NE];
#pragma unroll
  for (int e = 0; e < NE; ++e) acc[e] = 0.0;
  for (int i = 0; i < HD / 64; ++i) {
    float xv = xr[lane + i * 64];
#pragma unroll
    for (int e = 0; e < NE; ++e)
      acc[e] += (double)xv * (double)wgs[e * HD + lane + i * 64];
  }
#pragma unroll
  for (int e = 0; e < NE; ++e)
    for (int s = 32; s >= 1; s >>= 1) acc[e] += __shfl_xor(acc[e], s, 64);
  int e0 = 0; double m0 = acc[0];
  for (int e = 1; e < NE; ++e) if (acc[e] > m0) { m0 = acc[e]; e0 = e; }
  int e1 = -1; double m1 = -1e300;
  for (int e = 0; e < NE; ++e) if (e != e0 && acc[e] > m1) { m1 = acc[e]; e1 = e; }
  if (lane == 0) {
    double d = exp(m1 - m0);
    tidx[t * 2] = e0; tidx[t * 2 + 1] = e1;
    tw[t * 2] = (float)(1.0 / (1.0 + d));
    tw[t * 2 + 1] = (float)(d / (1.0 + d));
    atomicAdd(&counts[e0], 1);
    atomicAdd(&counts[e1], 1);
  }
}

__global__ void k_offsets(const int* __restrict__ counts, int* offs, int* cursors) {
  if (threadIdx.x == 0) {
    int s = 0;
    for (int e = 0; e < NE; ++e) { offs[e] = s; s += counts[e]; }
    offs[NE] = s;
  }
  if (threadIdx.x < NE) cursors[threadIdx.x] = 0;
}

__global__ __launch_bounds__(256) void k_scatter(
    const int* __restrict__ tidx, const int* __restrict__ offs,
    int* cursors, const float* __restrict__ tw,
    int* __restrict__ list, float* __restrict__ wlist) {
  int idx = blockIdx.x * 256 + threadIdx.x;
  if (idx >= AK) return;
  int e = tidx[idx];
  int p = atomicAdd(&cursors[e], 1);
  int a = offs[e] + p;
  list[a] = idx >> 1;
  wlist[a] = tw[idx];
}

// ---------------- fp32 -> bf16 conversion ----------------

__global__ __launch_bounds__(256) void k_cvtx(const float* __restrict__ in,
                                              u16* __restrict__ out) {
  int idx = blockIdx.x * 256 + threadIdx.x;
  const float4* in4 = (const float4*)in;
  float4 v = in4[idx];
  ushort4 o;
  o.x = f2bf(v.x); o.y = f2bf(v.y); o.z = f2bf(v.z); o.w = f2bf(v.w);
  ((ushort4*)out)[idx] = o;
}

// [R][C] fp32 -> [C][R] bf16, per expert (blockIdx.z). Vectorized both sides.
__global__ __launch_bounds__(256) void k_tconv(const float* __restrict__ in,
                                               u16* __restrict__ out, int R, int C) {
  __shared__ u16 tile[64][72];
  size_t base = (size_t)blockIdx.z * R * C;
  int r0 = blockIdx.y * 64, c0 = blockIdx.x * 64;
  int t = threadIdx.x;
  int rr = t >> 4;
  int cc = (t & 15) * 4;
#pragma unroll
  for (int i = 0; i < 4; ++i) {
    int r = i * 16 + rr;
    float4 v = *(const float4*)&in[base + (size_t)(r0 + r) * C + c0 + cc];
    tile[cc + 0][r] = f2bf(v.x);
    tile[cc + 1][r] = f2bf(v.y);
    tile[cc + 2][r] = f2bf(v.z);
    tile[cc + 3][r] = f2bf(v.w);
  }
  __syncthreads();
  int c = t >> 3;
  int ch = (t & 7) * 8;
#pragma unroll
  for (int j = 0; j < 2; ++j) {
    int cr = j * 32 + c;
    *(s16x8*)&out[base + (size_t)(c0 + cr) * R + r0 + ch] =
        *(const s16x8*)&tile[cr][ch];
  }
}

// ---------------- GEMM1: hidden = silu(x@w1) * (x@w3), gathered rows ----------------
// tile 128(M) x 64(N=I) x 64(K=H); 4 waves 2x2, wave tile 64x32.
// XCD-chunked 1-D grid, M fastest within chunk -> B N-panel stays in XCD L2.

__global__ __launch_bounds__(256, 2) void k_gemm1(
    const u16* __restrict__ xb, const u16* __restrict__ w1b,
    const u16* __restrict__ w3b, const int* __restrict__ list,
    const int* __restrict__ offs, u16* __restrict__ hidden) {
  const int MT = T_TOK / 128, NT = ID / 64;       // 64, 64
  int bid = blockIdx.x;
  int q = (MT * NT * NE) >> 3;                    // 4096 = one expert per XCD
  int flat = (bid & 7) * q + (bid >> 3);
  int mIdx = flat & (MT - 1);
  int rest = flat >> 6;
  int nIdx = rest & (NT - 1);
  int e = rest >> 6;

  int aoff = offs[e];
  int cnt = offs[e + 1] - aoff;
  int m0 = mIdx * 128;
  if (m0 >= cnt) return;
  int n0 = nIdx * 64;

  __shared__ u16 As[2][128 * 64];
  __shared__ u16 B1s[2][64 * 64];
  __shared__ u16 B3s[2][64 * 64];

  int tid = threadIdx.x, lane = tid & 63, wid = tid >> 6;
  int l8 = lane >> 3, c8 = lane & 7;
  int csrc = (c8 ^ l8) * 8;                 // inverse-swizzled source chunk (T2)

  const u16* gA[4];
#pragma unroll
  for (int i = 0; i < 4; ++i) {
    int row = (i * 4 + wid) * 8 + l8;
    int rr = m0 + row; if (rr > cnt - 1) rr = cnt - 1;
    int tok = list[aoff + rr];
    gA[i] = xb + (size_t)tok * HD + csrc;
  }
  const u16* gB1[2]; const u16* gB3[2];
#pragma unroll
  for (int i = 0; i < 2; ++i) {
    int n = (i * 4 + wid) * 8 + l8;
    size_t roww = ((size_t)e * ID + (n0 + n)) * HD + csrc;
    gB1[i] = w1b + roww;
    gB3[i] = w3b + roww;
  }

  f32x4 acc1[4][2], acc3[4][2];
#pragma unroll
  for (int m = 0; m < 4; ++m)
#pragma unroll
    for (int n = 0; n < 2; ++n) {
      acc1[m][n] = (f32x4){0.f, 0.f, 0.f, 0.f};
      acc3[m][n] = (f32x4){0.f, 0.f, 0.f, 0.f};
    }

  auto stage = [&](int buf, int k0) {
#pragma unroll
    for (int i = 0; i < 4; ++i) gld16(&As[buf][(i * 4 + wid) * 512], gA[i] + k0);
#pragma unroll
    for (int i = 0; i < 2; ++i) {
      gld16(&B1s[buf][(i * 4 + wid) * 512], gB1[i] + k0);
      gld16(&B3s[buf][(i * 4 + wid) * 512], gB3[i] + k0);
    }
  };

  int lane15 = lane & 15, lq = lane >> 4;
  int sw8 = lane15 & 7;
  int wr = wid >> 1, wc = wid & 1;
  int arow = wr * 64, bcol = wc * 32;

  stage(0, 0);
  for (int t = 0; t < HD / 64; ++t) {
    __syncthreads();                       // drains vmcnt -> buf[t&1] staged
    if (t < HD / 64 - 1) stage((t + 1) & 1, (t + 1) * 64);
    int buf = t & 1;
#pragma unroll
    for (int kk = 0; kk < 2; ++kk) {
      int ko = ((kk * 4 + lq) ^ sw8) * 8;  // swizzled physical chunk
      s16x8 a[4], b1[2], b3[2];
#pragma unroll
      for (int m = 0; m < 4; ++m)
        a[m] = *(const s16x8*)&As[buf][(arow + m * 16 + lane15) * 64 + ko];
#pragma unroll
      for (int n = 0; n < 2; ++n) {
        b1[n] = *(const s16x8*)&B1s[buf][(bcol + n * 16 + lane15) * 64 + ko];
        b3[n] = *(const s16x8*)&B3s[buf][(bcol + n * 16 + lane15) * 64 + ko];
      }
#pragma unroll
      for (int m = 0; m < 4; ++m)
#pragma unroll
        for (int n = 0; n < 2; ++n) {
          acc1[m][n] = __builtin_amdgcn_mfma_f32_16x16x32_bf16(a[m], b1[n], acc1[m][n], 0, 0, 0);
          acc3[m][n] = __builtin_amdgcn_mfma_f32_16x16x32_bf16(a[m], b3[n], acc3[m][n], 0, 0, 0);
        }
    }
  }

#pragma unroll
  for (int m = 0; m < 4; ++m)
#pragma unroll
    for (int j = 0; j < 4; ++j) {
      int grow = m0 + arow + m * 16 + lq * 4 + j;
      if (grow < cnt) {
        size_t rbase = (size_t)(aoff + grow) * ID + n0 + bcol;
#pragma unroll
        for (int n = 0; n < 2; ++n) {
          float v1 = acc1[m][n][j];
          float v3 = acc3[m][n][j];
          float s = v1 / (1.0f + __expf(-v1));
          hidden[rbase + n * 16 + lane15] = f2bf(s * v3);
        }
      }
    }
}

// ---------------- GEMM2: out[tok] += w * (hidden @ w2) ----------------
// tile 128(M) x 128(N=H) x 64(K=I); fused combine via fp32 atomicAdd
// (exactly 2 commutative adds per output element -> deterministic).

__global__ __launch_bounds__(256, 2) void k_gemm2(
    const u16* __restrict__ hidden, const u16* __restrict__ w2b,
    const int* __restrict__ offs, const int* __restrict__ list,
    const float* __restrict__ wlist, float* __restrict__ out) {
  const int MT = T_TOK / 128, NT = HD / 128;      // 64, 8
  int bid = blockIdx.x;
  int q = (MT * NT * NE) >> 3;                    // 512 = one expert per XCD
  int flat = (bid & 7) * q + (bid >> 3);
  int mIdx = flat & (MT - 1);
  int rest = flat >> 6;
  int nIdx = rest & (NT - 1);
  int e = rest >> 3;

  int aoff = offs[e];
  int cnt = offs[e + 1] - aoff;
  int m0 = mIdx * 128;
  if (m0 >= cnt) return;
  int n0 = nIdx * 128;

  __shared__ u16 As[2][128 * 64];
  __shared__ u16 Bs[2][128 * 64];

  int tid = threadIdx.x, lane = tid & 63, wid = tid >> 6;
  int l8 = lane >> 3, c8 = lane & 7;
  int csrc = (c8 ^ l8) * 8;

  const u16* gA[4]; const u16* gB[4];
#pragma unroll
  for (int i = 0; i < 4; ++i) {
    int row = (i * 4 + wid) * 8 + l8;
    gA[i] = hidden + (size_t)(aoff + m0 + row) * ID + csrc;   // APAD slack covers overrun
    gB[i] = w2b + ((size_t)e * HD + n0 + row) * ID + csrc;
  }

  f32x4 acc[4][4];
#pragma unroll
  for (int m = 0; m < 4; ++m)
#pragma unroll
    for (int n = 0; n < 4; ++n) acc[m][n] = (f32x4){0.f, 0.f, 0.f, 0.f};

  auto stage = [&](int buf, int k0) {
#pragma unroll
    for (int i = 0; i < 4; ++i) {
      gld16(&As[buf][(i * 4 + wid) * 512], gA[i] + k0);
      gld16(&Bs[buf][(i * 4 + wid) * 512], gB[i] + k0);
    }
  };

  int lane15 = lane & 15, lq = lane >> 4;
  int sw8 = lane15 & 7;
  int wr = wid >> 1, wc = wid & 1;
  int arow = wr * 64, bcol = wc * 64;

  stage(0, 0);
  for (int t = 0; t < ID / 64; ++t) {
    __syncthreads();
    if (t < ID / 64 - 1) stage((t + 1) & 1, (t + 1) * 64);
    int buf = t & 1;
#pragma unroll
    for (int kk = 0; kk < 2; ++kk) {
      int ko = ((kk * 4 + lq) ^ sw8) * 8;
      s16x8 a[4], b[4];
#pragma unroll
      for (int m = 0; m < 4; ++m)
        a[m] = *(const s16x8*)&As[buf][(arow + m * 16 + lane15) * 64 + ko];
#pragma unroll
      for (int n = 0; n < 4; ++n)
        b[n] = *(const s16x8*)&Bs[buf][(bcol + n * 16 + lane15) * 64 + ko];
#pragma unroll
      for (int m = 0; m < 4; ++m)
#pragma unroll
        for (int n = 0; n < 4; ++n)
          acc[m][n] = __builtin_amdgcn_mfma_f32_16x16x32_bf16(a[m], b[n], acc[m][n], 0, 0, 0);
    }
  }

#pragma unroll
  for (int m = 0; m < 4; ++m)
#pragma unroll
    for (int j = 0; j < 4; ++j) {
      int grow = m0 + arow + m * 16 + lq * 4 + j;
      if (grow < cnt) {
        int a = aoff + grow;
        int tok = list[a];
        float wgt = wlist[a];
        float* orow = out + (size_t)tok * HD + n0 + bcol;
#pragma unroll
        for (int n = 0; n < 4; ++n)
          atomicAdd(&orow[n * 16 + lane15], wgt * acc[m][n][j]);
      }
    }
}

// ---------------- host ----------------

extern "C" void kernel_launch(void* const* d_in, const int* in_sizes, int n_in,
                              void* d_out, int out_size, void* d_ws, size_t ws_size,
                              hipStream_t stream) {
  const float* x  = (const float*)d_in[0];
  const float* wg = (const float*)d_in[1];
  const float* w1 = (const float*)d_in[2];
  const float* w2 = (const float*)d_in[3];
  const float* w3 = (const float*)d_in[4];
  float* out = (float*)d_out;

  char* p = (char*)d_ws;
  auto alloc = [&](size_t bytes) {
    char* r = p;
    p += (bytes + 255) & ~(size_t)255;
    return r;
  };
  u16*   xb      = (u16*)alloc((size_t)T_TOK * HD * 2);       // 16 MiB
  u16*   w1b     = (u16*)alloc((size_t)NE * HD * ID * 2);     // 64 MiB  [E][I][H]
  u16*   w3b     = (u16*)alloc((size_t)NE * HD * ID * 2);     // 64 MiB  [E][I][H]
  u16*   w2b     = (u16*)alloc((size_t)NE * HD * ID * 2);     // 64 MiB  [E][H][I]
  u16*   hidden  = (u16*)alloc((size_t)APAD * ID * 2);        // 129 MiB
  int*   tidx    = (int*)alloc(AK * 4);
  float* tw      = (float*)alloc(AK * 4);
  int*   list    = (int*)alloc(AK * 4);
  float* wlist   = (float*)alloc(AK * 4);
  int*   counts  = (int*)alloc(64);
  int*   offs    = (int*)alloc(64);
  int*   cursors = (int*)alloc(64);
  (void)ws_size; (void)in_sizes; (void)n_in;

  hipMemsetAsync(d_out, 0, (size_t)out_size * 4, stream);

  k_init<<<1, 64, 0, stream>>>(counts);
  k_router<<<T_TOK / 4, 256, 0, stream>>>(x, wg, tidx, tw, counts);
  k_offsets<<<1, 64, 0, stream>>>(counts, offs, cursors);
  k_scatter<<<AK / 256, 256, 0, stream>>>(tidx, offs, cursors, tw, list, wlist);

  k_cvtx<<<(T_TOK * HD / 4) / 256, 256, 0, stream>>>(x, xb);
  dim3 g13(ID / 64, HD / 64, NE);
  k_tconv<<<g13, 256, 0, stream>>>(w1, w1b, HD, ID);   // [H][I] -> [I][H]
  k_tconv<<<g13, 256, 0, stream>>>(w3, w3b, HD, ID);
  dim3 g2(HD / 64, ID / 64, NE);
  k_tconv<<<g2, 256, 0, stream>>>(w2, w2b, ID, HD);    // [I][H] -> [H][I]

  k_gemm1<<<(T_TOK / 128) * (ID / 64) * NE, 256, 0, stream>>>(
      xb, w1b, w3b, list, offs, hidden);
  k_gemm2<<<(T_TOK / 128) * (HD / 128) * NE, 256, 0, stream>>>(
      hidden, w2b, offs, list, wlist, out);
}

// Round 5
// 1035.380 us; speedup vs baseline: 2.3705x; 1.1495x over previous
//
#include <hip/hip_runtime.h>

typedef unsigned short u16;
typedef __attribute__((ext_vector_type(4))) float f32x4;
typedef __attribute__((ext_vector_type(8))) short s16x8;

#define T_TOK 8192
#define HD    1024
#define ID    4096
#define NE    8
#define AK    (T_TOK * 2)      // total assignments (top-2)
#define APAD  (AK + 256)       // slack rows for 256-row A tiles
#define MTMAX 72               // max M-tiles: 16384/256 + 8 partials

#define BAR()   __builtin_amdgcn_s_barrier()
#define SB0()   __builtin_amdgcn_sched_barrier(0)
#define PRIO1() __builtin_amdgcn_s_setprio(1)
#define PRIO0() __builtin_amdgcn_s_setprio(0)
#define WAITV6() asm volatile("s_waitcnt vmcnt(6)" ::: "memory")
#define WAITV8() asm volatile("s_waitcnt vmcnt(8)" ::: "memory")
#define LGKM0()  do { asm volatile("s_waitcnt lgkmcnt(0)" ::: "memory"); SB0(); } while (0)

__device__ __forceinline__ u16 f2bf(float f) {
  unsigned u = __builtin_bit_cast(unsigned, f);
  u += 0x7FFFu + ((u >> 16) & 1u);   // round-to-nearest-even
  return (u16)(u >> 16);
}

__device__ __forceinline__ void gld16(u16* lds, const u16* g) {
  __builtin_amdgcn_global_load_lds(
      (const __attribute__((address_space(1))) unsigned int*)g,
      (__attribute__((address_space(3))) unsigned int*)lds, 16, 0, 0);
}

// ---------------- routing ----------------

__global__ void k_init(int* counts) {
  if (threadIdx.x < NE) counts[threadIdx.x] = 0;
}

__global__ __launch_bounds__(256) void k_router(
    const float* __restrict__ x, const float* __restrict__ wg,
    int* __restrict__ tidx, float* __restrict__ tw, int* __restrict__ counts) {
  __shared__ float wgs[NE * HD];            // transposed [e][h]
  int tid = threadIdx.x;
  for (int i = tid; i < NE * HD; i += 256) {
    int h = i >> 3, e = i & 7;
    wgs[e * HD + h] = wg[i];
  }
  __syncthreads();
  int lane = tid & 63, wid = tid >> 6;
  int t = blockIdx.x * 4 + wid;
  const float* xr = x + (size_t)t * HD;
  double acc[NE];
#pragma unroll
  for (int e = 0; e < NE; ++e) acc[e] = 0.0;
  for (int i = 0; i < HD / 64; ++i) {
    float xv = xr[lane + i * 64];
#pragma unroll
    for (int e = 0; e < NE; ++e)
      acc[e] += (double)xv * (double)wgs[e * HD + lane + i * 64];
  }
#pragma unroll
  for (int e = 0; e < NE; ++e)
    for (int s = 32; s >= 1; s >>= 1) acc[e] += __shfl_xor(acc[e], s, 64);
  int e0 = 0; double m0 = acc[0];
  for (int e = 1; e < NE; ++e) if (acc[e] > m0) { m0 = acc[e]; e0 = e; }
  int e1 = -1; double m1 = -1e300;
  for (int e = 0; e < NE; ++e) if (e != e0 && acc[e] > m1) { m1 = acc[e]; e1 = e; }
  if (lane == 0) {
    double d = exp(m1 - m0);
    tidx[t * 2] = e0; tidx[t * 2 + 1] = e1;
    tw[t * 2] = (float)(1.0 / (1.0 + d));
    tw[t * 2 + 1] = (float)(d / (1.0 + d));
    atomicAdd(&counts[e0], 1);
    atomicAdd(&counts[e1], 1);
  }
}

// offsets + compact M-tile list (expert-major)
__global__ void k_offsets(const int* __restrict__ counts, int* offs, int* cursors,
                          int* __restrict__ tiles, int* __restrict__ ntile) {
  if (threadIdx.x == 0) {
    int s = 0;
    for (int e = 0; e < NE; ++e) { offs[e] = s; s += counts[e]; }
    offs[NE] = s;
    int nt = 0;
    for (int e = 0; e < NE; ++e)
      for (int m0 = 0; m0 < counts[e]; m0 += 256)
        tiles[nt++] = (e << 16) | (m0 >> 8);
    ntile[0] = nt;
    for (int i = nt; i < MTMAX; ++i) tiles[i] = 0;
  }
  if (threadIdx.x < NE) cursors[threadIdx.x] = 0;
}

__global__ __launch_bounds__(256) void k_scatter(
    const int* __restrict__ tidx, const int* __restrict__ offs,
    int* cursors, const float* __restrict__ tw,
    int* __restrict__ list, float* __restrict__ wlist) {
  int idx = blockIdx.x * 256 + threadIdx.x;
  if (idx >= AK) return;
  int e = tidx[idx];
  int p = atomicAdd(&cursors[e], 1);
  int a = offs[e] + p;
  list[a] = idx >> 1;
  wlist[a] = tw[idx];
}

// ---------------- fp32 -> bf16 conversion ----------------

__global__ __launch_bounds__(256) void k_cvtx(const float* __restrict__ in,
                                              u16* __restrict__ out) {
  int idx = blockIdx.x * 256 + threadIdx.x;
  const float4* in4 = (const float4*)in;
  float4 v = in4[idx];
  ushort4 o;
  o.x = f2bf(v.x); o.y = f2bf(v.y); o.z = f2bf(v.z); o.w = f2bf(v.w);
  ((ushort4*)out)[idx] = o;
}

// w2 [E][I][H] fp32 -> w2b [E][H][I] bf16
__global__ __launch_bounds__(256) void k_tconv(const float* __restrict__ in,
                                               u16* __restrict__ out, int R, int C) {
  __shared__ u16 tile[64][72];
  size_t base = (size_t)blockIdx.z * R * C;
  int r0 = blockIdx.y * 64, c0 = blockIdx.x * 64;
  int t = threadIdx.x;
  int rr = t >> 4, cc = (t & 15) * 4;
#pragma unroll
  for (int i = 0; i < 4; ++i) {
    int r = i * 16 + rr;
    float4 v = *(const float4*)&in[base + (size_t)(r0 + r) * C + c0 + cc];
    tile[cc + 0][r] = f2bf(v.x);
    tile[cc + 1][r] = f2bf(v.y);
    tile[cc + 2][r] = f2bf(v.z);
    tile[cc + 3][r] = f2bf(v.w);
  }
  __syncthreads();
  int c = t >> 3, ch = (t & 7) * 8;
#pragma unroll
  for (int j = 0; j < 2; ++j) {
    int cr = j * 32 + c;
    *(s16x8*)&out[base + (size_t)(c0 + cr) * R + r0 + ch] =
        *(const s16x8*)&tile[cr][ch];
  }
}

// w1/w3 [E][H][I] fp32 -> w13b [E][2I][H] bf16, 16-row interleaved
__global__ __launch_bounds__(256) void k_tconv13(const float* __restrict__ w1,
                                                 const float* __restrict__ w3,
                                                 u16* __restrict__ out) {
  __shared__ u16 tile[64][72];
  int which = blockIdx.z >> 3, e = blockIdx.z & 7;
  const float* in = (which ? w3 : w1) + (size_t)e * HD * ID;
  int r0 = blockIdx.y * 64, c0 = blockIdx.x * 64;   // r=H-row, c=I-col
  int t = threadIdx.x;
  int rr = t >> 4, cc = (t & 15) * 4;
#pragma unroll
  for (int i = 0; i < 4; ++i) {
    int r = i * 16 + rr;
    float4 v = *(const float4*)&in[(size_t)(r0 + r) * ID + c0 + cc];
    tile[cc + 0][r] = f2bf(v.x);
    tile[cc + 1][r] = f2bf(v.y);
    tile[cc + 2][r] = f2bf(v.z);
    tile[cc + 3][r] = f2bf(v.w);
  }
  __syncthreads();
  int c = t >> 3, ch = (t & 7) * 8;
#pragma unroll
  for (int j = 0; j < 2; ++j) {
    int crow = c0 + j * 32 + c;                    // I-row
    int pr = ((crow >> 4) << 5) + which * 16 + (crow & 15);
    *(s16x8*)&out[((size_t)e * 2 * ID + pr) * HD + r0 + ch] =
        *(const s16x8*)&tile[j * 32 + c][ch];
  }
}

// ============ 8-phase GEMM core (256x256x64, 8 waves 2Mx4N) ============
// Wave slots remapped so half-tiles are CONTIGUOUS 128-row regions:
//   A row(mh,mm) = mh*128 + wr*64 + mm*16 ; B row(f) = (f>>1)*128 + wc*32 + (f&1)*16
// Stage schedule per iteration (tiles u=2i->buf0, v=2i+1->buf1), one half/phase:
//   p1:Ah1(v) p2:Bh1(v) p3:Ah0(u+2) p4:Bh0(u+2) p5:Ah1(u+2) p6:Bh1(u+2)
//   p7:Ah0(v+2) p8:Bh0(v+2);  waits: vmcnt(6)@p1,p5  vmcnt(8)@p4,p8.
// FIFO ledger verified: every region drained >=4 phases after issue, and every
// stage lands strictly after its region's last read (barrier-separated).

#define GEMM_CORE(NTK, NITER) \
  int wr = wid >> 2, wc = wid & 3; \
  int lane15 = lane & 15, lq = lane >> 4, sw8 = lane15 & 7; \
  f32x4 acc[8][4]; \
  _Pragma("unroll") for (int m = 0; m < 8; ++m) \
    _Pragma("unroll") for (int n = 0; n < 4; ++n) acc[m][n] = (f32x4){0.f,0.f,0.f,0.f}; \
  auto stgA = [&](int bb, int h, int kt) { \
    gld16(&As[bb][(h*128 + 0*64 + wid*8) * 64], gA[h*2+0] + kt*64); \
    gld16(&As[bb][(h*128 + 1*64 + wid*8) * 64], gA[h*2+1] + kt*64); }; \
  auto stgB = [&](int bb, int h, int kt) { \
    gld16(&Bs[bb][(h*128 + 0*64 + wid*8) * 64], gB[h*2+0] + kt*64); \
    gld16(&Bs[bb][(h*128 + 1*64 + wid*8) * 64], gB[h*2+1] + kt*64); }; \
  s16x8 a[4][2], b[2][2]; \
  auto rdA = [&](int bb, int mh) { \
    _Pragma("unroll") for (int mm = 0; mm < 4; ++mm) \
      _Pragma("unroll") for (int kk = 0; kk < 2; ++kk) \
        a[mm][kk] = *(const s16x8*)&As[bb][(mh*128 + wr*64 + mm*16 + lane15)*64 + (((kk*4+lq)^sw8)*8)]; }; \
  auto rdB = [&](int bb, int fh) { \
    _Pragma("unroll") for (int ff = 0; ff < 2; ++ff) \
      _Pragma("unroll") for (int kk = 0; kk < 2; ++kk) \
        b[ff][kk] = *(const s16x8*)&Bs[bb][(fh*128 + wc*32 + ff*16 + lane15)*64 + (((kk*4+lq)^sw8)*8)]; }; \
  auto mf = [&](int mh, int fh) { \
    _Pragma("unroll") for (int mm = 0; mm < 4; ++mm) \
      _Pragma("unroll") for (int ff = 0; ff < 2; ++ff) { \
        acc[mh*4+mm][fh*2+ff] = __builtin_amdgcn_mfma_f32_16x16x32_bf16(a[mm][0], b[ff][0], acc[mh*4+mm][fh*2+ff], 0, 0, 0); \
        acc[mh*4+mm][fh*2+ff] = __builtin_amdgcn_mfma_f32_16x16x32_bf16(a[mm][1], b[ff][1], acc[mh*4+mm][fh*2+ff], 0, 0, 0); } }; \
  /* prologue: S3..S8 of pseudo-iter -1 */ \
  stgA(0,0,0); stgB(0,0,0); stgA(0,1,0); stgB(0,1,0); stgA(1,0,1); stgB(1,0,1); \
  WAITV8(); BAR(); SB0(); \
  for (int i = 0; i < (NITER); ++i) { \
    int ku2 = (2*i+2) & ((NTK)-1), ku3 = (2*i+3) & ((NTK)-1); \
    /* p1 */ rdA(0,0); rdB(0,0); stgA(1,1,2*i+1); WAITV6(); BAR(); LGKM0(); PRIO1(); mf(0,0); PRIO0(); BAR(); SB0(); \
    /* p2 */ rdB(0,1); stgB(1,1,2*i+1); BAR(); LGKM0(); PRIO1(); mf(0,1); PRIO0(); BAR(); SB0(); \
    /* p3 */ rdA(0,1); rdB(0,0); stgA(0,0,ku2); BAR(); LGKM0(); PRIO1(); mf(1,0); PRIO0(); BAR(); SB0(); \
    /* p4 */ rdB(0,1); stgB(0,0,ku2); WAITV8(); BAR(); LGKM0(); PRIO1(); mf(1,1); PRIO0(); BAR(); SB0(); \
    /* p5 */ rdA(1,0); rdB(1,0); stgA(0,1,ku2); WAITV6(); BAR(); LGKM0(); PRIO1(); mf(0,0); PRIO0(); BAR(); SB0(); \
    /* p6 */ rdB(1,1); stgB(0,1,ku2); BAR(); LGKM0(); PRIO1(); mf(0,1); PRIO0(); BAR(); SB0(); \
    /* p7 */ rdA(1,1); rdB(1,0); stgA(1,0,ku3); BAR(); LGKM0(); PRIO1(); mf(1,0); PRIO0(); BAR(); SB0(); \
    /* p8 */ rdB(1,1); stgB(1,0,ku3); WAITV8(); BAR(); LGKM0(); PRIO1(); mf(1,1); PRIO0(); BAR(); SB0(); \
  }

// ---- GEMM1: hidden = silu(x@w1)*(x@w3); B = interleaved w13; gathered A ----
__global__ __launch_bounds__(512, 1) void k_gemm1(
    const u16* __restrict__ xb, const u16* __restrict__ w13b,
    const int* __restrict__ list, const int* __restrict__ offs,
    const int* __restrict__ tiles, const int* __restrict__ ntile,
    u16* __restrict__ hidden) {
  int ti = blockIdx.y;
  if (ti >= ntile[0]) return;
  int packed = tiles[ti];
  int e = packed >> 16;
  int m0 = (packed & 0xFFFF) << 8;
  int aoff = offs[e];
  int cnt = offs[e + 1] - aoff;
  int n0 = blockIdx.x * 256;          // over 2I interleaved

  __shared__ u16 As[2][256 * 64];
  __shared__ u16 Bs[2][256 * 64];

  int tid = threadIdx.x, lane = tid & 63, wid = tid >> 6;
  int l8 = lane >> 3, c8 = lane & 7;
  int csrc = (c8 ^ l8) * 8;

  const u16* gA[4]; const u16* gB[4];
#pragma unroll
  for (int h = 0; h < 2; ++h)
#pragma unroll
    for (int c = 0; c < 2; ++c) {
      int row = h * 128 + c * 64 + wid * 8 + l8;
      int rr = m0 + row; if (rr > cnt - 1) rr = cnt - 1;
      gA[h*2+c] = xb + (size_t)list[aoff + rr] * HD + csrc;
      gB[h*2+c] = w13b + ((size_t)e * 2 * ID + n0 + row) * HD + csrc;
    }

  GEMM_CORE(HD / 64, HD / 128)

  // epilogue: SwiGLU on fragment pairs
#pragma unroll
  for (int mh = 0; mh < 2; ++mh)
#pragma unroll
    for (int mm = 0; mm < 4; ++mm)
#pragma unroll
      for (int j = 0; j < 4; ++j) {
        int grow = m0 + mh * 128 + wr * 64 + mm * 16 + lq * 4 + j;
        if (grow < cnt) {
          size_t rbase = (size_t)(aoff + grow) * ID;
#pragma unroll
          for (int p = 0; p < 2; ++p) {
            float v1 = acc[mh*4+mm][2*p][j];
            float v3 = acc[mh*4+mm][2*p+1][j];
            float s = v1 / (1.0f + __expf(-v1));
            int icol = ((n0 + p * 128 + wc * 32) >> 1) + lane15;
            hidden[rbase + icol] = f2bf(s * v3);
          }
        }
      }
}

// ---- GEMM2: out[tok] += w * (hidden @ w2); K split in 2; atomic combine ----
__global__ __launch_bounds__(512, 1) void k_gemm2(
    const u16* __restrict__ hidden, const u16* __restrict__ w2b,
    const int* __restrict__ offs, const int* __restrict__ list,
    const float* __restrict__ wlist, const int* __restrict__ tiles,
    const int* __restrict__ ntile, float* __restrict__ out) {
  int ti = blockIdx.y;
  if (ti >= ntile[0]) return;
  int packed = tiles[ti];
  int e = packed >> 16;
  int m0 = (packed & 0xFFFF) << 8;
  int aoff = offs[e];
  int cnt = offs[e + 1] - aoff;
  int n0 = (blockIdx.x & 3) * 256;    // H cols
  int kc = (blockIdx.x >> 2) * 2048;  // K chunk base (elements)

  __shared__ u16 As[2][256 * 64];
  __shared__ u16 Bs[2][256 * 64];

  int tid = threadIdx.x, lane = tid & 63, wid = tid >> 6;
  int l8 = lane >> 3, c8 = lane & 7;
  int csrc = (c8 ^ l8) * 8;

  const u16* gA[4]; const u16* gB[4];
#pragma unroll
  for (int h = 0; h < 2; ++h)
#pragma unroll
    for (int c = 0; c < 2; ++c) {
      int row = h * 128 + c * 64 + wid * 8 + l8;
      gA[h*2+c] = hidden + (size_t)(aoff + m0 + row) * ID + kc + csrc;  // APAD slack
      gB[h*2+c] = w2b + ((size_t)e * HD + n0 + row) * ID + kc + csrc;
    }

  GEMM_CORE(2048 / 64, 2048 / 128)

#pragma unroll
  for (int mh = 0; mh < 2; ++mh)
#pragma unroll
    for (int mm = 0; mm < 4; ++mm)
#pragma unroll
      for (int j = 0; j < 4; ++j) {
        int grow = m0 + mh * 128 + wr * 64 + mm * 16 + lq * 4 + j;
        if (grow < cnt) {
          int a_ = aoff + grow;
          int tok = list[a_];
          float wgt = wlist[a_];
          float* orow = out + (size_t)tok * HD;
#pragma unroll
          for (int f = 0; f < 4; ++f) {
            int col = n0 + (f >> 1) * 128 + wc * 32 + (f & 1) * 16 + lane15;
            atomicAdd(&orow[col], wgt * acc[mh*4+mm][f][j]);
          }
        }
      }
}

// ---------------- host ----------------

extern "C" void kernel_launch(void* const* d_in, const int* in_sizes, int n_in,
                              void* d_out, int out_size, void* d_ws, size_t ws_size,
                              hipStream_t stream) {
  const float* x  = (const float*)d_in[0];
  const float* wg = (const float*)d_in[1];
  const float* w1 = (const float*)d_in[2];
  const float* w2 = (const float*)d_in[3];
  const float* w3 = (const float*)d_in[4];

  char* p = (char*)d_ws;
  auto alloc = [&](size_t bytes) {
    char* r = p;
    p += (bytes + 255) & ~(size_t)255;
    return r;
  };
  u16*   xb      = (u16*)alloc((size_t)T_TOK * HD * 2);           // 16 MiB
  u16*   w13b    = (u16*)alloc((size_t)NE * 2 * ID * HD * 2);     // 128 MiB [E][2I][H]
  u16*   w2b     = (u16*)alloc((size_t)NE * HD * ID * 2);         // 64 MiB  [E][H][I]
  u16*   hidden  = (u16*)alloc((size_t)APAD * ID * 2);            // 130 MiB
  int*   tidx    = (int*)alloc(AK * 4);
  float* tw      = (float*)alloc(AK * 4);
  int*   list    = (int*)alloc(AK * 4);
  float* wlist   = (float*)alloc(AK * 4);
  int*   counts  = (int*)alloc(64);
  int*   offs    = (int*)alloc(64);
  int*   cursors = (int*)alloc(64);
  int*   tiles   = (int*)alloc(MTMAX * 4);
  int*   ntile   = (int*)alloc(64);
  (void)ws_size; (void)in_sizes; (void)n_in;

  hipMemsetAsync(d_out, 0, (size_t)out_size * 4, stream);

  k_init<<<1, 64, 0, stream>>>(counts);
  k_router<<<T_TOK / 4, 256, 0, stream>>>(x, wg, tidx, tw, counts);
  k_offsets<<<1, 64, 0, stream>>>(counts, offs, cursors, tiles, ntile);
  k_scatter<<<AK / 256, 256, 0, stream>>>(tidx, offs, cursors, tw, list, wlist);

  k_cvtx<<<(T_TOK * HD / 4) / 256, 256, 0, stream>>>(x, xb);
  dim3 g13(ID / 64, HD / 64, 2 * NE);
  k_tconv13<<<g13, 256, 0, stream>>>(w1, w3, w13b);
  dim3 g2(HD / 64, ID / 64, NE);
  k_tconv<<<g2, 256, 0, stream>>>(w2, w2b, ID, HD);    // [I][H] -> [H][I]

  dim3 gg1(2 * ID / 256, MTMAX, 1);                    // x=32 (==0 mod 8: N-panel pinned per XCD)
  k_gemm1<<<gg1, 512, 0, stream>>>(xb, w13b, list, offs, tiles, ntile, hidden);
  dim3 gg2(8, MTMAX, 1);                               // x = 4 N-panels x 2 K-chunks
  k_gemm2<<<gg2, 512, 0, stream>>>(hidden, w2b, offs, list, wlist, tiles, ntile,
                                   (float*)d_out);
}

// Round 6
// 1011.872 us; speedup vs baseline: 2.4256x; 1.0232x over previous
//
#include <hip/hip_runtime.h>

typedef unsigned short u16;
typedef __attribute__((ext_vector_type(4))) float f32x4;
typedef __attribute__((ext_vector_type(8))) short s16x8;

#define T_TOK 8192
#define HD    1024
#define ID    4096
#define NE    8
#define AK    (T_TOK * 2)      // total assignments (top-2)
#define APAD  (AK + 256)       // slack rows for 256-row A tiles
#define MTMAX 72               // max M-tiles: 16384/256 + 8 partials

#define BAR()   __builtin_amdgcn_s_barrier()
#define SB0()   __builtin_amdgcn_sched_barrier(0)
#define PRIO1() __builtin_amdgcn_s_setprio(1)
#define PRIO0() __builtin_amdgcn_s_setprio(0)
#define WAITV6() asm volatile("s_waitcnt vmcnt(6)" ::: "memory")
#define WAITV8() asm volatile("s_waitcnt vmcnt(8)" ::: "memory")
#define LGKM0()  do { asm volatile("s_waitcnt lgkmcnt(0)" ::: "memory"); SB0(); } while (0)

__device__ __forceinline__ u16 f2bf(float f) {
  unsigned u = __builtin_bit_cast(unsigned, f);
  u += 0x7FFFu + ((u >> 16) & 1u);   // round-to-nearest-even
  return (u16)(u >> 16);
}

__device__ __forceinline__ void gld16(u16* lds, const u16* g) {
  __builtin_amdgcn_global_load_lds(
      (const __attribute__((address_space(1))) unsigned int*)g,
      (__attribute__((address_space(3))) unsigned int*)lds, 16, 0, 0);
}

// ---------------- routing helpers ----------------

__global__ void k_init(int* counts) {
  if (threadIdx.x < NE) counts[threadIdx.x] = 0;
}

// offsets + compact M-tile list (expert-major)
__global__ void k_offsets(const int* __restrict__ counts, int* offs, int* cursors,
                          int* __restrict__ tiles, int* __restrict__ ntile) {
  if (threadIdx.x == 0) {
    int s = 0;
    for (int e = 0; e < NE; ++e) { offs[e] = s; s += counts[e]; }
    offs[NE] = s;
    int nt = 0;
    for (int e = 0; e < NE; ++e)
      for (int m0 = 0; m0 < counts[e]; m0 += 256)
        tiles[nt++] = (e << 16) | (m0 >> 8);
    ntile[0] = nt;
    for (int i = nt; i < MTMAX; ++i) tiles[i] = 0;
  }
  if (threadIdx.x < NE) cursors[threadIdx.x] = 0;
}

__global__ __launch_bounds__(256) void k_scatter(
    const int* __restrict__ tidx, const int* __restrict__ offs,
    int* cursors, const float* __restrict__ tw,
    int* __restrict__ list, float* __restrict__ wlist) {
  int idx = blockIdx.x * 256 + threadIdx.x;
  if (idx >= AK) return;
  int e = tidx[idx];
  int p = atomicAdd(&cursors[e], 1);
  int a = offs[e] + p;
  list[a] = idx >> 1;
  wlist[a] = tw[idx];
}

// ---------------- fused prep: cvtx + tconv13 + tconv(w2) + router ----------------
// Region layout (flat 1-D grid, 256 threads each):
//   [0,            8192)  : x fp32 -> bf16
//   [8192,  8192+16384)   : w1/w3 [E][H][I] -> w13b [E][2I][H] interleaved
//   [24576, 24576+8192)   : w2 [E][I][H] -> w2b [E][H][I]
//   [32768, 32768+2048)   : router (fp64 logits, top-2, counts)

#define NB_CVT 8192
#define NB_T13 16384
#define NB_T2  8192
#define NB_RTR 2048

__global__ __launch_bounds__(256) void k_prep(
    const float* __restrict__ x, const float* __restrict__ wg,
    const float* __restrict__ w1, const float* __restrict__ w2,
    const float* __restrict__ w3,
    u16* __restrict__ xb, u16* __restrict__ w13b, u16* __restrict__ w2b,
    int* __restrict__ tidx, float* __restrict__ tw, int* __restrict__ counts) {
  __shared__ char smem[32768];
  int bid = blockIdx.x, t = threadIdx.x;

  if (bid < NB_CVT) {                       // ---- cvtx
    int idx = bid * 256 + t;
    float4 v = ((const float4*)x)[idx];
    ushort4 o;
    o.x = f2bf(v.x); o.y = f2bf(v.y); o.z = f2bf(v.z); o.w = f2bf(v.w);
    ((ushort4*)xb)[idx] = o;
    return;
  }
  if (bid < NB_CVT + NB_T13) {              // ---- tconv13
    u16 (*tile)[72] = (u16(*)[72])smem;
    int r = bid - NB_CVT;
    int bx = r & 63, by = (r >> 6) & 15, bz = r >> 10;  // x:I/64 y:H/64 z:2E
    int which = bz >> 3, e = bz & 7;
    const float* in = (which ? w3 : w1) + (size_t)e * HD * ID;
    int r0 = by * 64, c0 = bx * 64;                     // r=H-row, c=I-col
    int rr = t >> 4, cc = (t & 15) * 4;
#pragma unroll
    for (int i = 0; i < 4; ++i) {
      int rw = i * 16 + rr;
      float4 v = *(const float4*)&in[(size_t)(r0 + rw) * ID + c0 + cc];
      tile[cc + 0][rw] = f2bf(v.x);
      tile[cc + 1][rw] = f2bf(v.y);
      tile[cc + 2][rw] = f2bf(v.z);
      tile[cc + 3][rw] = f2bf(v.w);
    }
    __syncthreads();
    int c = t >> 3, ch = (t & 7) * 8;
#pragma unroll
    for (int j = 0; j < 2; ++j) {
      int crow = c0 + j * 32 + c;                       // I-row
      int pr = ((crow >> 4) << 5) + which * 16 + (crow & 15);
      *(s16x8*)&w13b[((size_t)e * 2 * ID + pr) * HD + r0 + ch] =
          *(const s16x8*)&tile[j * 32 + c][ch];
    }
    return;
  }
  if (bid < NB_CVT + NB_T13 + NB_T2) {      // ---- tconv w2: [I][H] -> [H][I]
    u16 (*tile)[72] = (u16(*)[72])smem;
    int r = bid - NB_CVT - NB_T13;
    int bx = r & 15, by = (r >> 4) & 63, bz = r >> 10;  // x:HD/64 y:ID/64 z:E
    const int R = ID, C = HD;
    size_t base = (size_t)bz * R * C;
    int r0 = by * 64, c0 = bx * 64;
    int rr = t >> 4, cc = (t & 15) * 4;
#pragma unroll
    for (int i = 0; i < 4; ++i) {
      int rw = i * 16 + rr;
      float4 v = *(const float4*)&w2[base + (size_t)(r0 + rw) * C + c0 + cc];
      tile[cc + 0][rw] = f2bf(v.x);
      tile[cc + 1][rw] = f2bf(v.y);
      tile[cc + 2][rw] = f2bf(v.z);
      tile[cc + 3][rw] = f2bf(v.w);
    }
    __syncthreads();
    int c = t >> 3, ch = (t & 7) * 8;
#pragma unroll
    for (int j = 0; j < 2; ++j) {
      int cr = j * 32 + c;
      *(s16x8*)&w2b[base + (size_t)(c0 + cr) * R + r0 + ch] =
          *(const s16x8*)&tile[cr][ch];
    }
    return;
  }
  {                                          // ---- router
    float* wgs = (float*)smem;               // [e][h] transposed, 32 KB
    int blockR = bid - NB_CVT - NB_T13 - NB_T2;
    for (int i = t; i < NE * HD; i += 256) {
      int h = i >> 3, e = i & 7;
      wgs[e * HD + h] = wg[i];
    }
    __syncthreads();
    int lane = t & 63, wid = t >> 6;
    int tok = blockR * 4 + wid;
    const float* xr = x + (size_t)tok * HD;
    double acc[NE];
#pragma unroll
    for (int e = 0; e < NE; ++e) acc[e] = 0.0;
    for (int i = 0; i < HD / 64; ++i) {
      float xv = xr[lane + i * 64];
#pragma unroll
      for (int e = 0; e < NE; ++e)
        acc[e] += (double)xv * (double)wgs[e * HD + lane + i * 64];
    }
#pragma unroll
    for (int e = 0; e < NE; ++e)
      for (int s = 32; s >= 1; s >>= 1) acc[e] += __shfl_xor(acc[e], s, 64);
    int e0 = 0; double m0 = acc[0];
    for (int e = 1; e < NE; ++e) if (acc[e] > m0) { m0 = acc[e]; e0 = e; }
    int e1 = -1; double m1 = -1e300;
    for (int e = 0; e < NE; ++e) if (e != e0 && acc[e] > m1) { m1 = acc[e]; e1 = e; }
    if (lane == 0) {
      double d = exp(m1 - m0);
      tidx[tok * 2] = e0; tidx[tok * 2 + 1] = e1;
      tw[tok * 2] = (float)(1.0 / (1.0 + d));
      tw[tok * 2 + 1] = (float)(d / (1.0 + d));
      atomicAdd(&counts[e0], 1);
      atomicAdd(&counts[e1], 1);
    }
  }
}

// ============ 8-phase GEMM core (256x256x64, 8 waves 2Mx4N) ============
// Half-tiles are contiguous 128-row regions:
//   A row(mh,mm) = mh*128 + wr*64 + mm*16 ; B row(f) = (f>>1)*128 + wc*32 + (f&1)*16
// Registers hold BOTH B halves (b[4][2]) so each half is ds_read exactly once
// per K-tile: reads per phase = [12,4,8,0] x2 = 48 b128/iter (was 64).
// Stage schedule (tiles u=2i->buf0, v=2i+1->buf1), one half-stage per phase:
//   p1:Ah1(v) p2:Bh1(v) p3:Ah0(u+2) p4:Bh0(u+2) p5:Ah1(u+2) p6:Bh1(u+2)
//   p7:Ah0(v+2) p8:Bh0(v+2);  waits: vmcnt(6)@p1,p5  vmcnt(8)@p4,p8.
// FIFO ledger verified: every region drained >=4 phases after issue; every
// overwrite-stage lands strictly after its region's last read.

#define GEMM_CORE(NTK, NITER) \
  int wr = wid >> 2, wc = wid & 3; \
  int lane15 = lane & 15, lq = lane >> 4, sw8 = lane15 & 7; \
  f32x4 acc[8][4]; \
  _Pragma("unroll") for (int m = 0; m < 8; ++m) \
    _Pragma("unroll") for (int n = 0; n < 4; ++n) acc[m][n] = (f32x4){0.f,0.f,0.f,0.f}; \
  auto stgA = [&](int bb, int h, int kt) { \
    gld16(&As[bb][(h*128 + 0*64 + wid*8) * 64], gA[h*2+0] + kt*64); \
    gld16(&As[bb][(h*128 + 1*64 + wid*8) * 64], gA[h*2+1] + kt*64); }; \
  auto stgB = [&](int bb, int h, int kt) { \
    gld16(&Bs[bb][(h*128 + 0*64 + wid*8) * 64], gB[h*2+0] + kt*64); \
    gld16(&Bs[bb][(h*128 + 1*64 + wid*8) * 64], gB[h*2+1] + kt*64); }; \
  s16x8 a[4][2], b[4][2]; \
  auto rdA = [&](int bb, int mh) { \
    _Pragma("unroll") for (int mm = 0; mm < 4; ++mm) \
      _Pragma("unroll") for (int kk = 0; kk < 2; ++kk) \
        a[mm][kk] = *(const s16x8*)&As[bb][(mh*128 + wr*64 + mm*16 + lane15)*64 + (((kk*4+lq)^sw8)*8)]; }; \
  auto rdB = [&](int bb, int fh) { \
    _Pragma("unroll") for (int ff = 0; ff < 2; ++ff) \
      _Pragma("unroll") for (int kk = 0; kk < 2; ++kk) \
        b[fh*2+ff][kk] = *(const s16x8*)&Bs[bb][(fh*128 + wc*32 + ff*16 + lane15)*64 + (((kk*4+lq)^sw8)*8)]; }; \
  auto mf = [&](int mh, int fh) { \
    _Pragma("unroll") for (int mm = 0; mm < 4; ++mm) \
      _Pragma("unroll") for (int ff = 0; ff < 2; ++ff) { \
        acc[mh*4+mm][fh*2+ff] = __builtin_amdgcn_mfma_f32_16x16x32_bf16(a[mm][0], b[fh*2+ff][0], acc[mh*4+mm][fh*2+ff], 0, 0, 0); \
        acc[mh*4+mm][fh*2+ff] = __builtin_amdgcn_mfma_f32_16x16x32_bf16(a[mm][1], b[fh*2+ff][1], acc[mh*4+mm][fh*2+ff], 0, 0, 0); } }; \
  /* prologue */ \
  stgA(0,0,0); stgB(0,0,0); stgA(0,1,0); stgB(0,1,0); stgA(1,0,1); stgB(1,0,1); \
  WAITV8(); BAR(); SB0(); \
  for (int i = 0; i < (NITER); ++i) { \
    int ku2 = (2*i+2) & ((NTK)-1), ku3 = (2*i+3) & ((NTK)-1); \
    /* p1 */ rdA(0,0); rdB(0,0); stgA(1,1,2*i+1); WAITV6(); BAR(); LGKM0(); PRIO1(); mf(0,0); PRIO0(); BAR(); SB0(); \
    /* p2 */ rdB(0,1); stgB(1,1,2*i+1); BAR(); LGKM0(); PRIO1(); mf(0,1); PRIO0(); BAR(); SB0(); \
    /* p3 */ rdA(0,1); stgA(0,0,ku2); BAR(); LGKM0(); PRIO1(); mf(1,0); PRIO0(); BAR(); SB0(); \
    /* p4 */ stgB(0,0,ku2); WAITV8(); BAR(); PRIO1(); mf(1,1); PRIO0(); BAR(); SB0(); \
    /* p5 */ rdA(1,0); rdB(1,0); stgA(0,1,ku2); WAITV6(); BAR(); LGKM0(); PRIO1(); mf(0,0); PRIO0(); BAR(); SB0(); \
    /* p6 */ rdB(1,1); stgB(0,1,ku2); BAR(); LGKM0(); PRIO1(); mf(0,1); PRIO0(); BAR(); SB0(); \
    /* p7 */ rdA(1,1); stgA(1,0,ku3); BAR(); LGKM0(); PRIO1(); mf(1,0); PRIO0(); BAR(); SB0(); \
    /* p8 */ stgB(1,0,ku3); WAITV8(); BAR(); PRIO1(); mf(1,1); PRIO0(); BAR(); SB0(); \
  }

// ---- GEMM1: hidden = silu(x@w1)*(x@w3); B = interleaved w13; gathered A ----
__global__ __launch_bounds__(512, 1) void k_gemm1(
    const u16* __restrict__ xb, const u16* __restrict__ w13b,
    const int* __restrict__ list, const int* __restrict__ offs,
    const int* __restrict__ tiles, const int* __restrict__ ntile,
    u16* __restrict__ hidden) {
  int ti = blockIdx.y;
  if (ti >= ntile[0]) return;
  int packed = tiles[ti];
  int e = packed >> 16;
  int m0 = (packed & 0xFFFF) << 8;
  int aoff = offs[e];
  int cnt = offs[e + 1] - aoff;
  int n0 = blockIdx.x * 256;          // over 2I interleaved

  __shared__ u16 As[2][256 * 64];
  __shared__ u16 Bs[2][256 * 64];

  int tid = threadIdx.x, lane = tid & 63, wid = tid >> 6;
  int l8 = lane >> 3, c8 = lane & 7;
  int csrc = (c8 ^ l8) * 8;

  const u16* gA[4]; const u16* gB[4];
#pragma unroll
  for (int h = 0; h < 2; ++h)
#pragma unroll
    for (int c = 0; c < 2; ++c) {
      int row = h * 128 + c * 64 + wid * 8 + l8;
      int rr = m0 + row; if (rr > cnt - 1) rr = cnt - 1;
      gA[h*2+c] = xb + (size_t)list[aoff + rr] * HD + csrc;
      gB[h*2+c] = w13b + ((size_t)e * 2 * ID + n0 + row) * HD + csrc;
    }

  GEMM_CORE(HD / 64, HD / 128)

  // epilogue: SwiGLU on fragment pairs
#pragma unroll
  for (int mh = 0; mh < 2; ++mh)
#pragma unroll
    for (int mm = 0; mm < 4; ++mm)
#pragma unroll
      for (int j = 0; j < 4; ++j) {
        int grow = m0 + mh * 128 + wr * 64 + mm * 16 + lq * 4 + j;
        if (grow < cnt) {
          size_t rbase = (size_t)(aoff + grow) * ID;
#pragma unroll
          for (int p = 0; p < 2; ++p) {
            float v1 = acc[mh*4+mm][2*p][j];
            float v3 = acc[mh*4+mm][2*p+1][j];
            float s = v1 / (1.0f + __expf(-v1));
            int icol = ((n0 + p * 128 + wc * 32) >> 1) + lane15;
            hidden[rbase + icol] = f2bf(s * v3);
          }
        }
      }
}

// ---- GEMM2: out[tok] += w * (hidden @ w2); K split in 4; atomic combine ----
__global__ __launch_bounds__(512, 1) void k_gemm2(
    const u16* __restrict__ hidden, const u16* __restrict__ w2b,
    const int* __restrict__ offs, const int* __restrict__ list,
    const float* __restrict__ wlist, const int* __restrict__ tiles,
    const int* __restrict__ ntile, float* __restrict__ out) {
  int ti = blockIdx.y;
  if (ti >= ntile[0]) return;
  int packed = tiles[ti];
  int e = packed >> 16;
  int m0 = (packed & 0xFFFF) << 8;
  int aoff = offs[e];
  int cnt = offs[e + 1] - aoff;
  int n0 = (blockIdx.x & 3) * 256;    // H cols
  int kc = (blockIdx.x >> 2) * 1024;  // K chunk base (elements)

  __shared__ u16 As[2][256 * 64];
  __shared__ u16 Bs[2][256 * 64];

  int tid = threadIdx.x, lane = tid & 63, wid = tid >> 6;
  int l8 = lane >> 3, c8 = lane & 7;
  int csrc = (c8 ^ l8) * 8;

  const u16* gA[4]; const u16* gB[4];
#pragma unroll
  for (int h = 0; h < 2; ++h)
#pragma unroll
    for (int c = 0; c < 2; ++c) {
      int row = h * 128 + c * 64 + wid * 8 + l8;
      gA[h*2+c] = hidden + (size_t)(aoff + m0 + row) * ID + kc + csrc;  // APAD slack
      gB[h*2+c] = w2b + ((size_t)e * HD + n0 + row) * ID + kc + csrc;
    }

  GEMM_CORE(1024 / 64, 1024 / 128)

#pragma unroll
  for (int mh = 0; mh < 2; ++mh)
#pragma unroll
    for (int mm = 0; mm < 4; ++mm)
#pragma unroll
      for (int j = 0; j < 4; ++j) {
        int grow = m0 + mh * 128 + wr * 64 + mm * 16 + lq * 4 + j;
        if (grow < cnt) {
          int a_ = aoff + grow;
          int tok = list[a_];
          float wgt = wlist[a_];
          float* orow = out + (size_t)tok * HD;
#pragma unroll
          for (int f = 0; f < 4; ++f) {
            int col = n0 + (f >> 1) * 128 + wc * 32 + (f & 1) * 16 + lane15;
            atomicAdd(&orow[col], wgt * acc[mh*4+mm][f][j]);
          }
        }
      }
}

// ---------------- host ----------------

extern "C" void kernel_launch(void* const* d_in, const int* in_sizes, int n_in,
                              void* d_out, int out_size, void* d_ws, size_t ws_size,
                              hipStream_t stream) {
  const float* x  = (const float*)d_in[0];
  const float* wg = (const float*)d_in[1];
  const float* w1 = (const float*)d_in[2];
  const float* w2 = (const float*)d_in[3];
  const float* w3 = (const float*)d_in[4];

  char* p = (char*)d_ws;
  auto alloc = [&](size_t bytes) {
    char* r = p;
    p += (bytes + 255) & ~(size_t)255;
    return r;
  };
  u16*   xb      = (u16*)alloc((size_t)T_TOK * HD * 2);           // 16 MiB
  u16*   w13b    = (u16*)alloc((size_t)NE * 2 * ID * HD * 2);     // 128 MiB [E][2I][H]
  u16*   w2b     = (u16*)alloc((size_t)NE * HD * ID * 2);         // 64 MiB  [E][H][I]
  u16*   hidden  = (u16*)alloc((size_t)APAD * ID * 2);            // 130 MiB
  int*   tidx    = (int*)alloc(AK * 4);
  float* tw      = (float*)alloc(AK * 4);
  int*   list    = (int*)alloc(AK * 4);
  float* wlist   = (float*)alloc(AK * 4);
  int*   counts  = (int*)alloc(64);
  int*   offs    = (int*)alloc(64);
  int*   cursors = (int*)alloc(64);
  int*   tiles   = (int*)alloc(MTMAX * 4);
  int*   ntile   = (int*)alloc(64);
  (void)ws_size; (void)in_sizes; (void)n_in;

  hipMemsetAsync(d_out, 0, (size_t)out_size * 4, stream);

  k_init<<<1, 64, 0, stream>>>(counts);
  k_prep<<<NB_CVT + NB_T13 + NB_T2 + NB_RTR, 256, 0, stream>>>(
      x, wg, w1, w2, w3, xb, w13b, w2b, tidx, tw, counts);
  k_offsets<<<1, 64, 0, stream>>>(counts, offs, cursors, tiles, ntile);
  k_scatter<<<AK / 256, 256, 0, stream>>>(tidx, offs, cursors, tw, list, wlist);

  dim3 gg1(2 * ID / 256, MTMAX, 1);                    // x=32: N-panel pinned per XCD
  k_gemm1<<<gg1, 512, 0, stream>>>(xb, w13b, list, offs, tiles, ntile, hidden);
  dim3 gg2(16, MTMAX, 1);                              // x = 4 N-panels x 4 K-chunks
  k_gemm2<<<gg2, 512, 0, stream>>>(hidden, w2b, offs, list, wlist, tiles, ntile,
                                   (float*)d_out);
}

// Round 7
// 876.910 us; speedup vs baseline: 2.7989x; 1.1539x over previous
//
#include <hip/hip_runtime.h>

typedef unsigned short u16;
typedef __attribute__((ext_vector_type(4))) float f32x4;
typedef __attribute__((ext_vector_type(8))) short s16x8;

#define T_TOK 8192
#define HD    1024
#define ID    4096
#define NE    8
#define AK    (T_TOK * 2)      // total assignments (top-2)
#define APAD  (AK + 256)       // slack rows for 256-row A tiles
#define MTMAX 72               // max M-tiles: 16384/256 + 8 partials

#define BAR()   __builtin_amdgcn_s_barrier()
#define SB0()   __builtin_amdgcn_sched_barrier(0)
#define PRIO1() __builtin_amdgcn_s_setprio(1)
#define PRIO0() __builtin_amdgcn_s_setprio(0)
#define WAITV6() asm volatile("s_waitcnt vmcnt(6)" ::: "memory")
#define WAITV8() asm volatile("s_waitcnt vmcnt(8)" ::: "memory")
#define LGKM0()  do { asm volatile("s_waitcnt lgkmcnt(0)" ::: "memory"); SB0(); } while (0)

__device__ __forceinline__ u16 f2bf(float f) {
  unsigned u = __builtin_bit_cast(unsigned, f);
  u += 0x7FFFu + ((u >> 16) & 1u);   // round-to-nearest-even
  return (u16)(u >> 16);
}

__device__ __forceinline__ float bf2f(u16 v) {
  unsigned u = (unsigned)v << 16;
  return __builtin_bit_cast(float, u);
}

__device__ __forceinline__ void gld16(u16* lds, const u16* g) {
  __builtin_amdgcn_global_load_lds(
      (const __attribute__((address_space(1))) unsigned int*)g,
      (__attribute__((address_space(3))) unsigned int*)lds, 16, 0, 0);
}

// ---------------- routing helpers ----------------

__global__ void k_init(int* counts) {
  if (threadIdx.x < NE) counts[threadIdx.x] = 0;
}

// offsets + compact M-tile list (expert-major)
__global__ void k_offsets(const int* __restrict__ counts, int* offs, int* cursors,
                          int* __restrict__ tiles, int* __restrict__ ntile) {
  if (threadIdx.x == 0) {
    int s = 0;
    for (int e = 0; e < NE; ++e) { offs[e] = s; s += counts[e]; }
    offs[NE] = s;
    int nt = 0;
    for (int e = 0; e < NE; ++e)
      for (int m0 = 0; m0 < counts[e]; m0 += 256)
        tiles[nt++] = (e << 16) | (m0 >> 8);
    ntile[0] = nt;
    for (int i = nt; i < MTMAX; ++i) tiles[i] = 0;
  }
  if (threadIdx.x < NE) cursors[threadIdx.x] = 0;
}

__global__ __launch_bounds__(256) void k_scatter(
    const int* __restrict__ tidx, const int* __restrict__ offs,
    int* cursors, int* __restrict__ list, int* __restrict__ pos) {
  int idx = blockIdx.x * 256 + threadIdx.x;
  if (idx >= AK) return;
  int e = tidx[idx];
  int p = atomicAdd(&cursors[e], 1);
  int a = offs[e] + p;
  list[a] = idx >> 1;
  pos[idx] = a;
}

// ---------------- fused prep: cvtx + tconv13 + tconv(w2) + router ----------------

#define NB_CVT 8192
#define NB_T13 16384
#define NB_T2  8192
#define NB_RTR 2048

__global__ __launch_bounds__(256) void k_prep(
    const float* __restrict__ x, const float* __restrict__ wg,
    const float* __restrict__ w1, const float* __restrict__ w2,
    const float* __restrict__ w3,
    u16* __restrict__ xb, u16* __restrict__ w13b, u16* __restrict__ w2b,
    int* __restrict__ tidx, float* __restrict__ tw, int* __restrict__ counts) {
  __shared__ char smem[32768];
  int bid = blockIdx.x, t = threadIdx.x;

  if (bid < NB_CVT) {                       // ---- cvtx
    int idx = bid * 256 + t;
    float4 v = ((const float4*)x)[idx];
    ushort4 o;
    o.x = f2bf(v.x); o.y = f2bf(v.y); o.z = f2bf(v.z); o.w = f2bf(v.w);
    ((ushort4*)xb)[idx] = o;
    return;
  }
  if (bid < NB_CVT + NB_T13) {              // ---- tconv13
    u16 (*tile)[72] = (u16(*)[72])smem;
    int r = bid - NB_CVT;
    int bx = r & 63, by = (r >> 6) & 15, bz = r >> 10;  // x:I/64 y:H/64 z:2E
    int which = bz >> 3, e = bz & 7;
    const float* in = (which ? w3 : w1) + (size_t)e * HD * ID;
    int r0 = by * 64, c0 = bx * 64;                     // r=H-row, c=I-col
    int rr = t >> 4, cc = (t & 15) * 4;
#pragma unroll
    for (int i = 0; i < 4; ++i) {
      int rw = i * 16 + rr;
      float4 v = *(const float4*)&in[(size_t)(r0 + rw) * ID + c0 + cc];
      tile[cc + 0][rw] = f2bf(v.x);
      tile[cc + 1][rw] = f2bf(v.y);
      tile[cc + 2][rw] = f2bf(v.z);
      tile[cc + 3][rw] = f2bf(v.w);
    }
    __syncthreads();
    int c = t >> 3, ch = (t & 7) * 8;
#pragma unroll
    for (int j = 0; j < 2; ++j) {
      int crow = c0 + j * 32 + c;                       // I-row
      int pr = ((crow >> 4) << 5) + which * 16 + (crow & 15);
      *(s16x8*)&w13b[((size_t)e * 2 * ID + pr) * HD + r0 + ch] =
          *(const s16x8*)&tile[j * 32 + c][ch];
    }
    return;
  }
  if (bid < NB_CVT + NB_T13 + NB_T2) {      // ---- tconv w2: [I][H] -> [H][I]
    u16 (*tile)[72] = (u16(*)[72])smem;
    int r = bid - NB_CVT - NB_T13;
    int bx = r & 15, by = (r >> 4) & 63, bz = r >> 10;  // x:HD/64 y:ID/64 z:E
    const int R = ID, C = HD;
    size_t base = (size_t)bz * R * C;
    int r0 = by * 64, c0 = bx * 64;
    int rr = t >> 4, cc = (t & 15) * 4;
#pragma unroll
    for (int i = 0; i < 4; ++i) {
      int rw = i * 16 + rr;
      float4 v = *(const float4*)&w2[base + (size_t)(r0 + rw) * C + c0 + cc];
      tile[cc + 0][rw] = f2bf(v.x);
      tile[cc + 1][rw] = f2bf(v.y);
      tile[cc + 2][rw] = f2bf(v.z);
      tile[cc + 3][rw] = f2bf(v.w);
    }
    __syncthreads();
    int c = t >> 3, ch = (t & 7) * 8;
#pragma unroll
    for (int j = 0; j < 2; ++j) {
      int cr = j * 32 + c;
      *(s16x8*)&w2b[base + (size_t)(c0 + cr) * R + r0 + ch] =
          *(const s16x8*)&tile[cr][ch];
    }
    return;
  }
  {                                          // ---- router
    float* wgs = (float*)smem;               // [e][h] transposed, 32 KB
    int blockR = bid - NB_CVT - NB_T13 - NB_T2;
    for (int i = t; i < NE * HD; i += 256) {
      int h = i >> 3, e = i & 7;
      wgs[e * HD + h] = wg[i];
    }
    __syncthreads();
    int lane = t & 63, wid = t >> 6;
    int tok = blockR * 4 + wid;
    const float* xr = x + (size_t)tok * HD;
    double acc[NE];
#pragma unroll
    for (int e = 0; e < NE; ++e) acc[e] = 0.0;
    for (int i = 0; i < HD / 64; ++i) {
      float xv = xr[lane + i * 64];
#pragma unroll
      for (int e = 0; e < NE; ++e)
        acc[e] += (double)xv * (double)wgs[e * HD + lane + i * 64];
    }
#pragma unroll
    for (int e = 0; e < NE; ++e)
      for (int s = 32; s >= 1; s >>= 1) acc[e] += __shfl_xor(acc[e], s, 64);
    int e0 = 0; double m0 = acc[0];
    for (int e = 1; e < NE; ++e) if (acc[e] > m0) { m0 = acc[e]; e0 = e; }
    int e1 = -1; double m1 = -1e300;
    for (int e = 0; e < NE; ++e) if (e != e0 && acc[e] > m1) { m1 = acc[e]; e1 = e; }
    if (lane == 0) {
      double d = exp(m1 - m0);
      tidx[tok * 2] = e0; tidx[tok * 2 + 1] = e1;
      tw[tok * 2] = (float)(1.0 / (1.0 + d));
      tw[tok * 2 + 1] = (float)(d / (1.0 + d));
      atomicAdd(&counts[e0], 1);
      atomicAdd(&counts[e1], 1);
    }
  }
}

// ============ 8-phase GEMM core (256x256x64, 8 waves 2Mx4N) ============
// (unchanged from r6 — verified ledger; b[4][2] holds both B halves)

#define GEMM_CORE(NTK, NITER) \
  int wr = wid >> 2, wc = wid & 3; \
  int lane15 = lane & 15, lq = lane >> 4, sw8 = lane15 & 7; \
  f32x4 acc[8][4]; \
  _Pragma("unroll") for (int m = 0; m < 8; ++m) \
    _Pragma("unroll") for (int n = 0; n < 4; ++n) acc[m][n] = (f32x4){0.f,0.f,0.f,0.f}; \
  auto stgA = [&](int bb, int h, int kt) { \
    gld16(&As[bb][(h*128 + 0*64 + wid*8) * 64], gA[h*2+0] + kt*64); \
    gld16(&As[bb][(h*128 + 1*64 + wid*8) * 64], gA[h*2+1] + kt*64); }; \
  auto stgB = [&](int bb, int h, int kt) { \
    gld16(&Bs[bb][(h*128 + 0*64 + wid*8) * 64], gB[h*2+0] + kt*64); \
    gld16(&Bs[bb][(h*128 + 1*64 + wid*8) * 64], gB[h*2+1] + kt*64); }; \
  s16x8 a[4][2], b[4][2]; \
  auto rdA = [&](int bb, int mh) { \
    _Pragma("unroll") for (int mm = 0; mm < 4; ++mm) \
      _Pragma("unroll") for (int kk = 0; kk < 2; ++kk) \
        a[mm][kk] = *(const s16x8*)&As[bb][(mh*128 + wr*64 + mm*16 + lane15)*64 + (((kk*4+lq)^sw8)*8)]; }; \
  auto rdB = [&](int bb, int fh) { \
    _Pragma("unroll") for (int ff = 0; ff < 2; ++ff) \
      _Pragma("unroll") for (int kk = 0; kk < 2; ++kk) \
        b[fh*2+ff][kk] = *(const s16x8*)&Bs[bb][(fh*128 + wc*32 + ff*16 + lane15)*64 + (((kk*4+lq)^sw8)*8)]; }; \
  auto mf = [&](int mh, int fh) { \
    _Pragma("unroll") for (int mm = 0; mm < 4; ++mm) \
      _Pragma("unroll") for (int ff = 0; ff < 2; ++ff) { \
        acc[mh*4+mm][fh*2+ff] = __builtin_amdgcn_mfma_f32_16x16x32_bf16(a[mm][0], b[fh*2+ff][0], acc[mh*4+mm][fh*2+ff], 0, 0, 0); \
        acc[mh*4+mm][fh*2+ff] = __builtin_amdgcn_mfma_f32_16x16x32_bf16(a[mm][1], b[fh*2+ff][1], acc[mh*4+mm][fh*2+ff], 0, 0, 0); } }; \
  /* prologue */ \
  stgA(0,0,0); stgB(0,0,0); stgA(0,1,0); stgB(0,1,0); stgA(1,0,1); stgB(1,0,1); \
  WAITV8(); BAR(); SB0(); \
  for (int i = 0; i < (NITER); ++i) { \
    int ku2 = (2*i+2) & ((NTK)-1), ku3 = (2*i+3) & ((NTK)-1); \
    /* p1 */ rdA(0,0); rdB(0,0); stgA(1,1,2*i+1); WAITV6(); BAR(); LGKM0(); PRIO1(); mf(0,0); PRIO0(); BAR(); SB0(); \
    /* p2 */ rdB(0,1); stgB(1,1,2*i+1); BAR(); LGKM0(); PRIO1(); mf(0,1); PRIO0(); BAR(); SB0(); \
    /* p3 */ rdA(0,1); stgA(0,0,ku2); BAR(); LGKM0(); PRIO1(); mf(1,0); PRIO0(); BAR(); SB0(); \
    /* p4 */ stgB(0,0,ku2); WAITV8(); BAR(); PRIO1(); mf(1,1); PRIO0(); BAR(); SB0(); \
    /* p5 */ rdA(1,0); rdB(1,0); stgA(0,1,ku2); WAITV6(); BAR(); LGKM0(); PRIO1(); mf(0,0); PRIO0(); BAR(); SB0(); \
    /* p6 */ rdB(1,1); stgB(0,1,ku2); BAR(); LGKM0(); PRIO1(); mf(0,1); PRIO0(); BAR(); SB0(); \
    /* p7 */ rdA(1,1); stgA(1,0,ku3); BAR(); LGKM0(); PRIO1(); mf(1,0); PRIO0(); BAR(); SB0(); \
    /* p8 */ stgB(1,0,ku3); WAITV8(); BAR(); PRIO1(); mf(1,1); PRIO0(); BAR(); SB0(); \
  }

// ---- GEMM1: hidden = silu(x@w1)*(x@w3); B = interleaved w13; gathered A ----
__global__ __launch_bounds__(512, 1) void k_gemm1(
    const u16* __restrict__ xb, const u16* __restrict__ w13b,
    const int* __restrict__ list, const int* __restrict__ offs,
    const int* __restrict__ tiles, const int* __restrict__ ntile,
    u16* __restrict__ hidden) {
  int ti = blockIdx.y;
  if (ti >= ntile[0]) return;
  int packed = tiles[ti];
  int e = packed >> 16;
  int m0 = (packed & 0xFFFF) << 8;
  int aoff = offs[e];
  int cnt = offs[e + 1] - aoff;
  int n0 = blockIdx.x * 256;          // over 2I interleaved

  __shared__ u16 As[2][256 * 64];
  __shared__ u16 Bs[2][256 * 64];

  int tid = threadIdx.x, lane = tid & 63, wid = tid >> 6;
  int l8 = lane >> 3, c8 = lane & 7;
  int csrc = (c8 ^ l8) * 8;

  const u16* gA[4]; const u16* gB[4];
#pragma unroll
  for (int h = 0; h < 2; ++h)
#pragma unroll
    for (int c = 0; c < 2; ++c) {
      int row = h * 128 + c * 64 + wid * 8 + l8;
      int rr = m0 + row; if (rr > cnt - 1) rr = cnt - 1;
      gA[h*2+c] = xb + (size_t)list[aoff + rr] * HD + csrc;
      gB[h*2+c] = w13b + ((size_t)e * 2 * ID + n0 + row) * HD + csrc;
    }

  GEMM_CORE(HD / 64, HD / 128)

  // epilogue: SwiGLU on fragment pairs
#pragma unroll
  for (int mh = 0; mh < 2; ++mh)
#pragma unroll
    for (int mm = 0; mm < 4; ++mm)
#pragma unroll
      for (int j = 0; j < 4; ++j) {
        int grow = m0 + mh * 128 + wr * 64 + mm * 16 + lq * 4 + j;
        if (grow < cnt) {
          size_t rbase = (size_t)(aoff + grow) * ID;
#pragma unroll
          for (int p = 0; p < 2; ++p) {
            float v1 = acc[mh*4+mm][2*p][j];
            float v3 = acc[mh*4+mm][2*p+1][j];
            float s = v1 / (1.0f + __expf(-v1));
            int icol = ((n0 + p * 128 + wc * 32) >> 1) + lane15;
            hidden[rbase + icol] = f2bf(s * v3);
          }
        }
      }
}

// ---- GEMM2: yp[kchunk][a] = hidden_chunk @ w2_chunk (bf16 partials, no atomics) ----
__global__ __launch_bounds__(512, 1) void k_gemm2(
    const u16* __restrict__ hidden, const u16* __restrict__ w2b,
    const int* __restrict__ offs, const int* __restrict__ tiles,
    const int* __restrict__ ntile,
    u16* __restrict__ yp0, u16* __restrict__ yp3) {
  int ti = blockIdx.y;
  if (ti >= ntile[0]) return;
  int packed = tiles[ti];
  int e = packed >> 16;
  int m0 = (packed & 0xFFFF) << 8;
  int aoff = offs[e];
  int cnt = offs[e + 1] - aoff;
  int n0 = (blockIdx.x & 3) * 256;    // H cols
  int kidx = blockIdx.x >> 2;
  int kc = kidx * 1024;               // K chunk base (elements)

  __shared__ u16 As[2][256 * 64];
  __shared__ u16 Bs[2][256 * 64];

  int tid = threadIdx.x, lane = tid & 63, wid = tid >> 6;
  int l8 = lane >> 3, c8 = lane & 7;
  int csrc = (c8 ^ l8) * 8;

  const u16* gA[4]; const u16* gB[4];
#pragma unroll
  for (int h = 0; h < 2; ++h)
#pragma unroll
    for (int c = 0; c < 2; ++c) {
      int row = h * 128 + c * 64 + wid * 8 + l8;
      gA[h*2+c] = hidden + (size_t)(aoff + m0 + row) * ID + kc + csrc;  // APAD slack
      gB[h*2+c] = w2b + ((size_t)e * HD + n0 + row) * ID + kc + csrc;
    }

  GEMM_CORE(1024 / 64, 1024 / 128)

  u16* yp = (kidx < 3) ? yp0 + (size_t)kidx * AK * HD : yp3;
#pragma unroll
  for (int mh = 0; mh < 2; ++mh)
#pragma unroll
    for (int mm = 0; mm < 4; ++mm)
#pragma unroll
      for (int j = 0; j < 4; ++j) {
        int grow = m0 + mh * 128 + wr * 64 + mm * 16 + lq * 4 + j;
        if (grow < cnt) {
          u16* yrow = yp + (size_t)(aoff + grow) * HD;
#pragma unroll
          for (int f = 0; f < 4; ++f) {
            int col = n0 + (f >> 1) * 128 + wc * 32 + (f & 1) * 16 + lane15;
            yrow[col] = f2bf(acc[mh*4+mm][f][j]);
          }
        }
      }
}

// ---- combine: out[t] = w0*sum_k yp[k][p0] + w1*sum_k yp[k][p1] ----
__global__ __launch_bounds__(256) void k_combine(
    const u16* __restrict__ yp0, const u16* __restrict__ yp3,
    const int* __restrict__ pos, const float* __restrict__ tw,
    float* __restrict__ out) {
  int t = blockIdx.x;
  int c = threadIdx.x * 4;
  int a0 = pos[t * 2], a1 = pos[t * 2 + 1];
  float w0 = tw[t * 2], w1 = tw[t * 2 + 1];
  float s0[4] = {0.f, 0.f, 0.f, 0.f}, s1[4] = {0.f, 0.f, 0.f, 0.f};
#pragma unroll
  for (int k = 0; k < 4; ++k) {
    const u16* yp = (k < 3) ? yp0 + (size_t)k * AK * HD : yp3;
    ushort4 v0 = *(const ushort4*)&yp[(size_t)a0 * HD + c];
    ushort4 v1 = *(const ushort4*)&yp[(size_t)a1 * HD + c];
    s0[0] += bf2f(v0.x); s0[1] += bf2f(v0.y); s0[2] += bf2f(v0.z); s0[3] += bf2f(v0.w);
    s1[0] += bf2f(v1.x); s1[1] += bf2f(v1.y); s1[2] += bf2f(v1.z); s1[3] += bf2f(v1.w);
  }
  float4 o;
  o.x = w0 * s0[0] + w1 * s1[0];
  o.y = w0 * s0[1] + w1 * s1[1];
  o.z = w0 * s0[2] + w1 * s1[2];
  o.w = w0 * s0[3] + w1 * s1[3];
  *(float4*)&out[(size_t)t * HD + c] = o;
}

// ---------------- host ----------------

extern "C" void kernel_launch(void* const* d_in, const int* in_sizes, int n_in,
                              void* d_out, int out_size, void* d_ws, size_t ws_size,
                              hipStream_t stream) {
  const float* x  = (const float*)d_in[0];
  const float* wg = (const float*)d_in[1];
  const float* w1 = (const float*)d_in[2];
  const float* w2 = (const float*)d_in[3];
  const float* w3 = (const float*)d_in[4];

  char* p = (char*)d_ws;
  auto alloc = [&](size_t bytes) {
    char* r = p;
    p += (bytes + 255) & ~(size_t)255;
    return r;
  };
  u16*   xb      = (u16*)alloc((size_t)T_TOK * HD * 2);           // 16 MiB
  u16*   w13b    = (u16*)alloc((size_t)NE * 2 * ID * HD * 2);     // 128 MiB [E][2I][H]
  u16*   w2b     = (u16*)alloc((size_t)NE * HD * ID * 2);         // 64 MiB  [E][H][I]
  u16*   hidden  = (u16*)alloc((size_t)APAD * ID * 2);            // 130 MiB
  u16*   yp3     = (u16*)alloc((size_t)AK * HD * 2);              // 34 MiB (4th partial)
  int*   tidx    = (int*)alloc(AK * 4);
  float* tw      = (float*)alloc(AK * 4);
  int*   list    = (int*)alloc(AK * 4);
  int*   pos     = (int*)alloc(AK * 4);
  int*   counts  = (int*)alloc(64);
  int*   offs    = (int*)alloc(64);
  int*   cursors = (int*)alloc(64);
  int*   tiles   = (int*)alloc(MTMAX * 4);
  int*   ntile   = (int*)alloc(64);
  (void)ws_size; (void)in_sizes; (void)n_in; (void)out_size;

  // yp partials 0..2 alias w13b (dead after gemm1; stream order serializes)
  u16* yp0 = w13b;

  k_init<<<1, 64, 0, stream>>>(counts);
  k_prep<<<NB_CVT + NB_T13 + NB_T2 + NB_RTR, 256, 0, stream>>>(
      x, wg, w1, w2, w3, xb, w13b, w2b, tidx, tw, counts);
  k_offsets<<<1, 64, 0, stream>>>(counts, offs, cursors, tiles, ntile);
  k_scatter<<<AK / 256, 256, 0, stream>>>(tidx, offs, cursors, list, pos);

  dim3 gg1(2 * ID / 256, MTMAX, 1);                    // x=32: N-panel pinned per XCD
  k_gemm1<<<gg1, 512, 0, stream>>>(xb, w13b, list, offs, tiles, ntile, hidden);
  dim3 gg2(16, MTMAX, 1);                              // x = 4 N-panels x 4 K-chunks
  k_gemm2<<<gg2, 512, 0, stream>>>(hidden, w2b, offs, tiles, ntile, yp0, yp3);
  k_combine<<<T_TOK, 256, 0, stream>>>(yp0, yp3, pos, tw, (float*)d_out);
}